// Round 10
// baseline (847.639 us; speedup 1.0000x reference)
//
#include <hip/hip_runtime.h>
#include <hip/hip_bf16.h>

// Problem dims
#define NNODE 32
#define NB    64
#define NDIM  32
#define NSTEP 8
#define NE    992
#define NTT   16

typedef __bf16 bf16;
typedef __attribute__((ext_vector_type(8))) __bf16 bf16x8;
typedef __attribute__((ext_vector_type(4))) __bf16 bf16x4;
typedef __attribute__((ext_vector_type(4))) float  f32x4;

__device__ __forceinline__ f32x4 mfma_bf16(bf16x8 a, bf16x8 b, f32x4 c) {
  return __builtin_amdgcn_mfma_f32_16x16x32_bf16(a, b, c, 0, 0, 0);
}
__device__ __forceinline__ float sigm(float x) { return 1.0f / (1.0f + __expf(-x)); }
__device__ __forceinline__ float tanh_f(float x) {
  x = fminf(fmaxf(x, -15.0f), 15.0f);
  float e = __expf(2.0f * x);
  return (e - 1.0f) / (e + 1.0f);
}

// ---------------------------------------------------------------------------
// Weight swizzles. B-frag (K=64): slot ((nt*KF+kf)*64+lane)*8+j holds
// B[kf*32+(lane>>4)*8+j][nt*16+(lane&15)].
// W1P (K=32): msg@W1 split into x_row@W1_top (nt 0..11) | x_col@W1_bot (12..23).
// ---------------------------------------------------------------------------
__global__ void prep_weights(
    const float* __restrict__ msgW1, const float* __restrict__ msgW2,
    const float* __restrict__ geWi,  const float* __restrict__ geWh,
    const float* __restrict__ gnWi,  const float* __restrict__ gnWh,
    const float* __restrict__ oW1,   const float* __restrict__ oW2,
    const float* __restrict__ oW3,
    bf16* __restrict__ W1P, bf16* __restrict__ B2,
    bf16* __restrict__ GI, bf16* __restrict__ GH,
    bf16* __restrict__ GN,
    bf16* __restrict__ OW1s, bf16* __restrict__ OW2s, bf16* __restrict__ OW3s) {
  int u = blockIdx.x * 256 + threadIdx.x;
  if (u < 12288) {
    int k = u >> 12, i = (u >> 6) & 63, h = u & 63;
    int kf = i >> 5, quad = (i >> 3) & 3, j = i & 7;
    int nn = k * 64 + h, nt = nn >> 4, lane = quad * 16 + (nn & 15);
    int slot = ((nt * 2 + kf) * 64 + lane) * 8 + j;
    GI[slot] = (bf16)geWi[u];
    GH[slot] = (bf16)geWh[u];
    int ntl = h >> 4, lane2 = quad * 16 + (h & 15);
    int slot2 = k * 4096 + ((ntl * 2 + kf) * 64 + lane2) * 8 + j;
    B2[slot2] = (bf16)msgW2[u];
    // W1P: K=32 frag; nt3 = kf*12 + (n>>4)
    int loc = i & 31, q3 = loc >> 3, j3 = loc & 7;
    int nt3 = kf * 12 + (nn >> 4);
    int lane3 = q3 * 16 + (nn & 15);
    W1P[(nt3 * 64 + lane3) * 8 + j3] = (bf16)msgW1[u];
  } else if (u < 39936) {
    int v = u - 12288;
    int kk = v / 9216, rem = v % 9216, i = rem / 96, h = rem % 96;
    int kf = i >> 5, loc = i & 31, quad = loc >> 3, j = loc & 7;
    int nn = kk * 96 + h, nt = nn >> 4, lane = quad * 16 + (nn & 15);
    int slot = ((nt * 3 + kf) * 64 + lane) * 8 + j;
    GN[slot]         = (bf16)gnWi[v];
    GN[27648 + slot] = (bf16)gnWh[v];
  } else if (u < 46080) {
    int v = u - 39936; int i = v >> 6, h = v & 63;
    int kf = i >> 5, loc = i & 31, quad = loc >> 3, j = loc & 7;
    int nt = h >> 4, lane = quad * 16 + (h & 15);
    OW1s[((nt * 3 + kf) * 64 + lane) * 8 + j] = (bf16)oW1[v];
  } else if (u < 50176) {
    int v = u - 46080; int i = v >> 6, h = v & 63;
    int kf = i >> 5, quad = (i >> 3) & 3, j = i & 7;
    int nt = h >> 4, lane = quad * 16 + (h & 15);
    OW2s[((nt * 2 + kf) * 64 + lane) * 8 + j] = (bf16)oW2[v];
  } else if (u < 52224) {
    int v = u - 50176; int i = v >> 5, h = v & 31;
    int kf = i >> 5, quad = (i >> 3) & 3, j = i & 7;
    int nt = h >> 4, lane = quad * 16 + (h & 15);
    OW3s[((nt * 2 + kf) * 64 + lane) * 8 + j] = (bf16)oW3[v];
  }
}

// t=0 input into xf (fp32), layout [n][b][d].
__global__ void copy_x0(const float* __restrict__ x, float* __restrict__ xf) {
  int u = blockIdx.x * 256 + threadIdx.x;  // 65536
  int n = u >> 11, b = (u >> 5) & 63, d = u & 31;
  xf[u] = x[((b * 32 + n) * 32 + d) * 8 + 0];
}

// ---------------------------------------------------------------------------
// P precompute for ground-truth steps: P[t][n][b][0..383] (P1 | P2), FP32.
// Grid 256 blocks = 8t x 32n. Each wave: its 16-batch block x ALL 24 nt.
// (Round-9 bug: nt=wv*6+s covered only 1/4 of Pbuf; rest stayed poison.)
// ---------------------------------------------------------------------------
__global__ __launch_bounds__(256) void p8_kernel(
    const float* __restrict__ x, const bf16* __restrict__ W1P,
    float* __restrict__ Pbuf) {
  __shared__ __align__(16) bf16 XA[64][40];
  int t = blockIdx.x >> 5, n = blockIdx.x & 31;
  int tid = threadIdx.x;
  for (int u = tid; u < 2048; u += 256) {
    int b = u >> 5, d = u & 31;
    XA[b][d] = (bf16)x[((b * 32 + n) * 32 + d) * 8 + t];
  }
  __syncthreads();
  int wv = tid >> 6, ln = tid & 63, quad = ln >> 4, l16 = ln & 15;
  bf16x8 a = *(const bf16x8*)&XA[wv * 16 + l16][quad * 8];
  float* Pt = Pbuf + ((size_t)(t * 32 + n) * 64) * 384;
#pragma unroll
  for (int nt = 0; nt < 24; nt++) {
    bf16x8 bfr = *(const bf16x8*)&W1P[(nt * 64 + ln) * 8];
    f32x4 c = {0.f, 0.f, 0.f, 0.f};
    c = mfma_bf16(a, bfr, c);
#pragma unroll
    for (int rr = 0; rr < 4; rr++)
      Pt[(size_t)(wv * 16 + quad * 4 + rr) * 384 + nt * 16 + l16] = c[rr];
  }
}

// build layer-2 A-fragment chunk from fp32 P halves + bias, relu, bf16
__device__ __forceinline__ bf16x8 mk_h1(const float* b1p, const float* b2p,
                                        const float* biasL, int col) {
  f32x4 pa0 = *(const f32x4*)(b1p + col);
  f32x4 pa1 = *(const f32x4*)(b1p + col + 4);
  f32x4 pb0 = *(const f32x4*)(b2p + col);
  f32x4 pb1 = *(const f32x4*)(b2p + col + 4);
  bf16x8 h;
#pragma unroll
  for (int j = 0; j < 4; j++) {
    float v0 = pa0[j] + pb0[j] + biasL[col + j];
    float v1 = pa1[j] + pb1[j] + biasL[col + 4 + j];
    h[j]     = (bf16)(v0 > 0.f ? v0 : 0.f);
    h[4 + j] = (bf16)(v1 > 0.f ? v1 : 0.f);
  }
  return h;
}

// ---------------------------------------------------------------------------
// mix precompute for t=0..7 (fully parallel): layer2 + z-mix from Pbuf (fp32).
// t==0 -> hed (initial state); t>=1 -> mixbuf[t-1]. Grid 8*496 blocks.
// ---------------------------------------------------------------------------
__global__ __launch_bounds__(256, 2) void mix8_kernel(
    const float* __restrict__ Pbuf, const int* __restrict__ es,
    const float* __restrict__ z,
    const bf16* __restrict__ B2,
    const float* __restrict__ mb1, const float* __restrict__ mb2,
    bf16* __restrict__ hed, bf16* __restrict__ mixbuf) {
  __shared__ float zL[2][64][3];
  __shared__ float biasL[384];  // mb1 | mb2
  int t = blockIdx.x / 496, pair = blockIdx.x % 496;
  int e0 = pair * 2, tid = threadIdx.x;
  int cn0 = es[e0], rn0 = es[NE + e0];
  int cn1 = es[e0 + 1], rn1 = es[NE + e0 + 1];
  for (int u = tid; u < 384; u += 256)
    biasL[u] = (u < 192) ? mb1[u] : mb2[u - 192];
  for (int u = tid; u < 384; u += 256) {
    int pe = u / 192, rem = u % 192, b = rem / 3, k = rem % 3;
    zL[pe][b][k] = z[(b * NE + e0 + pe) * 3 + k];
  }
  __syncthreads();
  int wv = tid >> 6, ln = tid & 63, quad = ln >> 4, l16 = ln & 15;
  int m = wv * 16 + l16;
  bf16x8 a2[2][3][2];
#pragma unroll
  for (int pe = 0; pe < 2; pe++) {
    int rn = pe ? rn1 : rn0, cnn = pe ? cn1 : cn0;
    const float* b1p = Pbuf + ((size_t)(t * 32 + rn) * 64 + m) * 384;
    const float* b2p = Pbuf + ((size_t)(t * 32 + cnn) * 64 + m) * 384 + 192;
#pragma unroll
    for (int kt = 0; kt < 3; kt++)
#pragma unroll
      for (int kf = 0; kf < 2; kf++)
        a2[pe][kt][kf] = mk_h1(b1p, b2p, biasL, kt * 64 + kf * 32 + quad * 8);
  }
  f32x4 acc2[2][12];
#pragma unroll
  for (int pe = 0; pe < 2; pe++)
#pragma unroll
    for (int q = 0; q < 12; q++) { f32x4 zz = {0.f,0.f,0.f,0.f}; acc2[pe][q] = zz; }
#pragma unroll
  for (int kt = 0; kt < 3; kt++)
#pragma unroll
    for (int nt = 0; nt < 4; nt++) {
      bf16x8 w0 = *(const bf16x8*)&B2[kt * 4096 + (nt * 2 + 0) * 512 + ln * 8];
      bf16x8 w1 = *(const bf16x8*)&B2[kt * 4096 + (nt * 2 + 1) * 512 + ln * 8];
#pragma unroll
      for (int pe = 0; pe < 2; pe++) {
        acc2[pe][kt * 4 + nt] = mfma_bf16(a2[pe][kt][0], w0, acc2[pe][kt * 4 + nt]);
        acc2[pe][kt * 4 + nt] = mfma_bf16(a2[pe][kt][1], w1, acc2[pe][kt * 4 + nt]);
      }
    }
#pragma unroll
  for (int pe = 0; pe < 2; pe++) {
    bf16* dst = (t == 0) ? (hed + (size_t)(e0 + pe) * 4096)
                         : (mixbuf + ((size_t)(t - 1) * NE + e0 + pe) * 4096);
#pragma unroll
    for (int r = 0; r < 4; r++) {
      int b = wv * 16 + quad * 4 + r;
      float z0 = zL[pe][b][0], z1 = zL[pe][b][1], z2 = zL[pe][b][2];
#pragma unroll
      for (int nt = 0; nt < 4; nt++) {
        int o = nt * 16 + l16;
        float h0 = acc2[pe][nt][r]     + biasL[192 + o];       h0 = h0 > 0.f ? h0 : 0.f;
        float h1 = acc2[pe][4 + nt][r] + biasL[192 + 64 + o];  h1 = h1 > 0.f ? h1 : 0.f;
        float h2 = acc2[pe][8 + nt][r] + biasL[192 + 128 + o]; h2 = h2 > 0.f ? h2 : 0.f;
        dst[b * 64 + o] = (bf16)((h0 * z0 + h1 * z1 + h2 * z2) * (1.0f / 3.0f));
      }
    }
  }
}

// ---------------------------------------------------------------------------
// GRU-only edge step for t=1..7: mix from mixbuf, state in hed. 496 blocks.
// ---------------------------------------------------------------------------
__global__ __launch_bounds__(256, 2) void gru_step(
    const bf16* __restrict__ mixbuf, bf16* __restrict__ hed,
    const bf16* __restrict__ GI, const bf16* __restrict__ GH,
    const float* __restrict__ gbi, const float* __restrict__ gbh, int t) {
  __shared__ __align__(16) bf16 S[2][64][72];
  __shared__ float gb[384];  // gbi | gbh
  int e0 = blockIdx.x * 2, tid = threadIdx.x;
  for (int u = tid; u < 384; u += 256)
    gb[u] = (u < 192) ? gbi[u] : gbh[u - 192];
  int wv = tid >> 6, ln = tid & 63, quad = ln >> 4, l16 = ln & 15;
  int m = wv * 16 + l16;
  bf16x8 ai[2][2], ah[2][2];
#pragma unroll
  for (int pe = 0; pe < 2; pe++) {
    const bf16* mrow = mixbuf + ((size_t)(t - 1) * NE + e0 + pe) * 4096 + m * 64;
    const bf16* hrow = hed + (size_t)(e0 + pe) * 4096 + m * 64;
#pragma unroll
    for (int kf = 0; kf < 2; kf++) {
      ai[pe][kf] = *(const bf16x8*)(mrow + kf * 32 + quad * 8);
      ah[pe][kf] = *(const bf16x8*)(hrow + kf * 32 + quad * 8);
    }
  }
  f32x4 gri[2][8], gni[2][4], gnh[2][4];
#pragma unroll
  for (int pe = 0; pe < 2; pe++) {
#pragma unroll
    for (int q = 0; q < 8; q++) { f32x4 zz = {0.f,0.f,0.f,0.f}; gri[pe][q] = zz; }
#pragma unroll
    for (int q = 0; q < 4; q++) { f32x4 zz = {0.f,0.f,0.f,0.f}; gni[pe][q] = zz; gnh[pe][q] = zz; }
  }
#pragma unroll
  for (int nt = 0; nt < 8; nt++) {
    bf16x8 wi0 = *(const bf16x8*)&GI[(nt * 2 + 0) * 512 + ln * 8];
    bf16x8 wi1 = *(const bf16x8*)&GI[(nt * 2 + 1) * 512 + ln * 8];
    bf16x8 wh0 = *(const bf16x8*)&GH[(nt * 2 + 0) * 512 + ln * 8];
    bf16x8 wh1 = *(const bf16x8*)&GH[(nt * 2 + 1) * 512 + ln * 8];
#pragma unroll
    for (int pe = 0; pe < 2; pe++) {
      gri[pe][nt] = mfma_bf16(ai[pe][0], wi0, gri[pe][nt]);
      gri[pe][nt] = mfma_bf16(ai[pe][1], wi1, gri[pe][nt]);
      gri[pe][nt] = mfma_bf16(ah[pe][0], wh0, gri[pe][nt]);
      gri[pe][nt] = mfma_bf16(ah[pe][1], wh1, gri[pe][nt]);
    }
  }
#pragma unroll
  for (int nt = 8; nt < 12; nt++) {
    bf16x8 wi0 = *(const bf16x8*)&GI[(nt * 2 + 0) * 512 + ln * 8];
    bf16x8 wi1 = *(const bf16x8*)&GI[(nt * 2 + 1) * 512 + ln * 8];
    bf16x8 wh0 = *(const bf16x8*)&GH[(nt * 2 + 0) * 512 + ln * 8];
    bf16x8 wh1 = *(const bf16x8*)&GH[(nt * 2 + 1) * 512 + ln * 8];
#pragma unroll
    for (int pe = 0; pe < 2; pe++) {
      gni[pe][nt - 8] = mfma_bf16(ai[pe][0], wi0, gni[pe][nt - 8]);
      gni[pe][nt - 8] = mfma_bf16(ai[pe][1], wi1, gni[pe][nt - 8]);
      gnh[pe][nt - 8] = mfma_bf16(ah[pe][0], wh0, gnh[pe][nt - 8]);
      gnh[pe][nt - 8] = mfma_bf16(ah[pe][1], wh1, gnh[pe][nt - 8]);
    }
  }
#pragma unroll
  for (int pe = 0; pe < 2; pe++)
#pragma unroll
    for (int r = 0; r < 4; r++) {
      int b = wv * 16 + quad * 4 + r;
#pragma unroll
      for (int nt = 0; nt < 4; nt++) {
        int o = nt * 16 + l16;
        float xr = gri[pe][nt][r]     + gb[o]      + gb[192 + o];
        float xi = gri[pe][4 + nt][r] + gb[64 + o] + gb[192 + 64 + o];
        float xn = gni[pe][nt][r] + gb[128 + o];
        float hn = gnh[pe][nt][r] + gb[192 + 128 + o];
        float rg = sigm(xr);
        float ig = sigm(xi);
        float ng = tanh_f(xn + rg * hn);
        float hv = (float)hed[(size_t)(e0 + pe) * 4096 + b * 64 + o];
        S[pe][b][o] = (bf16)((1.0f - ig) * ng + ig * hv);
      }
    }
  __syncthreads();
  for (int u = tid; u < 1024; u += 256) {
    int pe = u >> 9, c = u & 511, b = c >> 3, j = c & 7;
    *(bf16x8*)(hed + (size_t)(e0 + pe) * 4096 + b * 64 + j * 8) = *(const bf16x8*)&S[pe][b][j * 8];
  }
}

// ---------------------------------------------------------------------------
// Full edge step for t=8..15: layer2 from Pcur (fp32) + mix + GRU. 496 blocks.
// ---------------------------------------------------------------------------
__global__ __launch_bounds__(256, 2) void edge_full(
    const float* __restrict__ Pcur, const int* __restrict__ es,
    const float* __restrict__ z,
    const bf16* __restrict__ B2,
    const float* __restrict__ mb1, const float* __restrict__ mb2,
    const bf16* __restrict__ GI, const bf16* __restrict__ GH,
    const float* __restrict__ gbi, const float* __restrict__ gbh,
    bf16* __restrict__ hed) {
  __shared__ __align__(16) bf16 S[2][64][72];   // mix, then new state
  __shared__ float zL[2][64][3];
  __shared__ float biasL[768];  // mb1 | mb2 | gbi | gbh
  int e0 = blockIdx.x * 2, tid = threadIdx.x;
  int cn0 = es[e0], rn0 = es[NE + e0];
  int cn1 = es[e0 + 1], rn1 = es[NE + e0 + 1];
  for (int u = tid; u < 768; u += 256)
    biasL[u] = (u < 192) ? mb1[u] : (u < 384) ? mb2[u - 192]
             : (u < 576) ? gbi[u - 384] : gbh[u - 576];
  for (int u = tid; u < 384; u += 256) {
    int pe = u / 192, rem = u % 192, b = rem / 3, k = rem % 3;
    zL[pe][b][k] = z[(b * NE + e0 + pe) * 3 + k];
  }
  __syncthreads();
  int wv = tid >> 6, ln = tid & 63, quad = ln >> 4, l16 = ln & 15;
  int m = wv * 16 + l16;
  bf16x8 a2[2][3][2];
#pragma unroll
  for (int pe = 0; pe < 2; pe++) {
    int rn = pe ? rn1 : rn0, cnn = pe ? cn1 : cn0;
    const float* b1p = Pcur + ((size_t)rn * 64 + m) * 384;
    const float* b2p = Pcur + ((size_t)cnn * 64 + m) * 384 + 192;
#pragma unroll
    for (int kt = 0; kt < 3; kt++)
#pragma unroll
      for (int kf = 0; kf < 2; kf++)
        a2[pe][kt][kf] = mk_h1(b1p, b2p, biasL, kt * 64 + kf * 32 + quad * 8);
  }
  f32x4 acc2[2][12];
#pragma unroll
  for (int pe = 0; pe < 2; pe++)
#pragma unroll
    for (int q = 0; q < 12; q++) { f32x4 zz = {0.f,0.f,0.f,0.f}; acc2[pe][q] = zz; }
#pragma unroll
  for (int kt = 0; kt < 3; kt++)
#pragma unroll
    for (int nt = 0; nt < 4; nt++) {
      bf16x8 w0 = *(const bf16x8*)&B2[kt * 4096 + (nt * 2 + 0) * 512 + ln * 8];
      bf16x8 w1 = *(const bf16x8*)&B2[kt * 4096 + (nt * 2 + 1) * 512 + ln * 8];
#pragma unroll
      for (int pe = 0; pe < 2; pe++) {
        acc2[pe][kt * 4 + nt] = mfma_bf16(a2[pe][kt][0], w0, acc2[pe][kt * 4 + nt]);
        acc2[pe][kt * 4 + nt] = mfma_bf16(a2[pe][kt][1], w1, acc2[pe][kt * 4 + nt]);
      }
    }
#pragma unroll
  for (int pe = 0; pe < 2; pe++)
#pragma unroll
    for (int r = 0; r < 4; r++) {
      int b = wv * 16 + quad * 4 + r;
      float z0 = zL[pe][b][0], z1 = zL[pe][b][1], z2 = zL[pe][b][2];
#pragma unroll
      for (int nt = 0; nt < 4; nt++) {
        int o = nt * 16 + l16;
        float h0 = acc2[pe][nt][r]     + biasL[192 + o];       h0 = h0 > 0.f ? h0 : 0.f;
        float h1 = acc2[pe][4 + nt][r] + biasL[192 + 64 + o];  h1 = h1 > 0.f ? h1 : 0.f;
        float h2 = acc2[pe][8 + nt][r] + biasL[192 + 128 + o]; h2 = h2 > 0.f ? h2 : 0.f;
        S[pe][b][o] = (bf16)((h0 * z0 + h1 * z1 + h2 * z2) * (1.0f / 3.0f));
      }
    }
  __syncthreads();
  bf16x8 ai[2][2], ah[2][2];
#pragma unroll
  for (int pe = 0; pe < 2; pe++) {
    const bf16* hrow = hed + (size_t)(e0 + pe) * 4096 + m * 64;
#pragma unroll
    for (int kf = 0; kf < 2; kf++) {
      ai[pe][kf] = *(const bf16x8*)&S[pe][m][kf * 32 + quad * 8];
      ah[pe][kf] = *(const bf16x8*)(hrow + kf * 32 + quad * 8);
    }
  }
  f32x4 gri[2][8], gni[2][4], gnh[2][4];
#pragma unroll
  for (int pe = 0; pe < 2; pe++) {
#pragma unroll
    for (int q = 0; q < 8; q++) { f32x4 zz = {0.f,0.f,0.f,0.f}; gri[pe][q] = zz; }
#pragma unroll
    for (int q = 0; q < 4; q++) { f32x4 zz = {0.f,0.f,0.f,0.f}; gni[pe][q] = zz; gnh[pe][q] = zz; }
  }
#pragma unroll
  for (int nt = 0; nt < 8; nt++) {
    bf16x8 wi0 = *(const bf16x8*)&GI[(nt * 2 + 0) * 512 + ln * 8];
    bf16x8 wi1 = *(const bf16x8*)&GI[(nt * 2 + 1) * 512 + ln * 8];
    bf16x8 wh0 = *(const bf16x8*)&GH[(nt * 2 + 0) * 512 + ln * 8];
    bf16x8 wh1 = *(const bf16x8*)&GH[(nt * 2 + 1) * 512 + ln * 8];
#pragma unroll
    for (int pe = 0; pe < 2; pe++) {
      gri[pe][nt] = mfma_bf16(ai[pe][0], wi0, gri[pe][nt]);
      gri[pe][nt] = mfma_bf16(ai[pe][1], wi1, gri[pe][nt]);
      gri[pe][nt] = mfma_bf16(ah[pe][0], wh0, gri[pe][nt]);
      gri[pe][nt] = mfma_bf16(ah[pe][1], wh1, gri[pe][nt]);
    }
  }
#pragma unroll
  for (int nt = 8; nt < 12; nt++) {
    bf16x8 wi0 = *(const bf16x8*)&GI[(nt * 2 + 0) * 512 + ln * 8];
    bf16x8 wi1 = *(const bf16x8*)&GI[(nt * 2 + 1) * 512 + ln * 8];
    bf16x8 wh0 = *(const bf16x8*)&GH[(nt * 2 + 0) * 512 + ln * 8];
    bf16x8 wh1 = *(const bf16x8*)&GH[(nt * 2 + 1) * 512 + ln * 8];
#pragma unroll
    for (int pe = 0; pe < 2; pe++) {
      gni[pe][nt - 8] = mfma_bf16(ai[pe][0], wi0, gni[pe][nt - 8]);
      gni[pe][nt - 8] = mfma_bf16(ai[pe][1], wi1, gni[pe][nt - 8]);
      gnh[pe][nt - 8] = mfma_bf16(ah[pe][0], wh0, gnh[pe][nt - 8]);
      gnh[pe][nt - 8] = mfma_bf16(ah[pe][1], wh1, gnh[pe][nt - 8]);
    }
  }
#pragma unroll
  for (int pe = 0; pe < 2; pe++)
#pragma unroll
    for (int r = 0; r < 4; r++) {
      int b = wv * 16 + quad * 4 + r;
#pragma unroll
      for (int nt = 0; nt < 4; nt++) {
        int o = nt * 16 + l16;
        float xr = gri[pe][nt][r]     + biasL[384 + o]      + biasL[576 + o];
        float xi = gri[pe][4 + nt][r] + biasL[384 + 64 + o] + biasL[576 + 64 + o];
        float xn = gni[pe][nt][r] + biasL[384 + 128 + o];
        float hn = gnh[pe][nt][r] + biasL[576 + 128 + o];
        float rg = sigm(xr);
        float ig = sigm(xi);
        float ng = tanh_f(xn + rg * hn);
        float hv = (float)hed[(size_t)(e0 + pe) * 4096 + b * 64 + o];
        S[pe][b][o] = (bf16)((1.0f - ig) * ng + ig * hv);
      }
    }
  __syncthreads();
  for (int u = tid; u < 1024; u += 256) {
    int pe = u >> 9, c = u & 511, b = c >> 3, j = c & 7;
    *(bf16x8*)(hed + (size_t)(e0 + pe) * 4096 + b * 64 + j * 8) = *(const bf16x8*)&S[pe][b][j * 8];
  }
}

// ---------------------------------------------------------------------------
// Node kernel: agg + node GRU (MFMA) + out-MLP + next-input + Pcur epilogue.
// 128 blocks.
// ---------------------------------------------------------------------------
__global__ __launch_bounds__(256) void node_kernel(
    const float* __restrict__ x, const bf16* __restrict__ hed,
    float* __restrict__ xf, float* __restrict__ hnode,
    const bf16* __restrict__ GN,
    const float* __restrict__ gnbi, const float* __restrict__ gnbh,
    const bf16* __restrict__ OW1, const float* __restrict__ ob1,
    const bf16* __restrict__ OW2, const float* __restrict__ ob2,
    const bf16* __restrict__ OW3, const float* __restrict__ ob3,
    const bf16* __restrict__ W1P, float* __restrict__ Pcur,
    float* __restrict__ out, int t) {
  __shared__ float aggf[16][64];
  __shared__ float xinf[16][32];
  __shared__ float hvf[16][96];
  __shared__ __align__(16) bf16 c0b[16][112];
  __shared__ __align__(16) bf16 hvb[16][112];
  __shared__ float gsum[2][16][290];
  __shared__ __align__(16) bf16 cnb[16][112];
  __shared__ __align__(16) bf16 s1b[16][112];
  __shared__ __align__(16) bf16 s2b[16][112];
  __shared__ __align__(16) bf16 xnb[16][40];
  int nq = blockIdx.x, n = nq >> 2, q = nq & 3;
  int tid = threadIdx.x;
  {
    int r = tid >> 4, o4 = tid & 15;
    const bf16x4* bp = (const bf16x4*)hed + (size_t)n * 31 * 1024 + (q * 16 + r) * 16 + o4;
    float sx = 0.f, sy = 0.f, sz = 0.f, sw = 0.f;
#pragma unroll
    for (int e2 = 0; e2 < 31; e2++) {
      bf16x4 v = bp[e2 * 1024];
      sx += (float)v[0]; sy += (float)v[1]; sz += (float)v[2]; sw += (float)v[3];
    }
    const float inv = 1.0f / 31.0f;
    sx *= inv; sy *= inv; sz *= inv; sw *= inv;
    int o = o4 * 4;
    aggf[r][o] = sx; aggf[r][o + 1] = sy; aggf[r][o + 2] = sz; aggf[r][o + 3] = sw;
    c0b[r][32 + o] = (bf16)sx; c0b[r][33 + o] = (bf16)sy;
    c0b[r][34 + o] = (bf16)sz; c0b[r][35 + o] = (bf16)sw;
  }
  if (tid < 128) {
    int r = tid >> 3, d0 = (tid & 7) * 4;
    int b = q * 16 + r;
#pragma unroll
    for (int k = 0; k < 4; k++) {
      float v = xf[n * 2048 + b * 32 + d0 + k];
      xinf[r][d0 + k] = v;
      c0b[r][d0 + k] = (bf16)v;
    }
  }
  if (t > 0) {
    int r = tid >> 4, cb = (tid & 15) * 6;
    int row = n * 64 + q * 16 + r;
#pragma unroll
    for (int k = 0; k < 6; k++) {
      float v = hnode[row * 96 + cb + k];
      hvf[r][cb + k] = v;
      hvb[r][cb + k] = (bf16)v;
    }
  }
  __syncthreads();
  int wv = tid >> 6, ln = tid & 63, quad = ln >> 4, l16 = ln & 15;
  if (t > 0) {
    int mat = wv >> 1, sel = wv & 1;
    const bf16(*Ab)[112] = mat ? hvb : c0b;
    bf16x8 af[3];
#pragma unroll
    for (int kf = 0; kf < 3; kf++)
      af[kf] = *(const bf16x8*)&Ab[l16][kf * 32 + quad * 8];
    const bf16* W = GN + mat * 27648;
    f32x4 accn[9];
#pragma unroll
    for (int q2 = 0; q2 < 9; q2++) { f32x4 zz = {0.f,0.f,0.f,0.f}; accn[q2] = zz; }
#pragma unroll
    for (int nt2 = 0; nt2 < 9; nt2++) {
      int nt = sel * 9 + nt2;
#pragma unroll
      for (int kf = 0; kf < 3; kf++) {
        bf16x8 bfrag = *(const bf16x8*)&W[((nt * 3 + kf) * 64 + ln) * 8];
        accn[nt2] = mfma_bf16(af[kf], bfrag, accn[nt2]);
      }
    }
#pragma unroll
    for (int nt2 = 0; nt2 < 9; nt2++) {
      int col = (sel * 9 + nt2) * 16 + l16;
#pragma unroll
      for (int rr = 0; rr < 4; rr++)
        gsum[mat][quad * 4 + rr][col] = accn[nt2][rr];
    }
  }
  __syncthreads();
  {
    int r = tid >> 4, cb = (tid & 15) * 6;
    int row = n * 64 + q * 16 + r;
#pragma unroll
    for (int k = 0; k < 6; k++) {
      int c = cb + k;
      float v;
      if (t > 0) {
        float xr = gsum[0][r][c] + gnbi[c] + gsum[1][r][c] + gnbh[c];
        float xi = gsum[0][r][96 + c] + gnbi[96 + c] + gsum[1][r][96 + c] + gnbh[96 + c];
        float xn = gsum[0][r][192 + c] + gnbi[192 + c];
        float hn = gsum[1][r][192 + c] + gnbh[192 + c];
        float rg = sigm(xr);
        float ig = sigm(xi);
        float ng = tanh_f(xn + rg * hn);
        v = (1.0f - ig) * ng + ig * hvf[r][c];
      } else {
        v = (c < 32) ? xinf[r][c] : aggf[r][c - 32];
      }
      cnb[r][c] = (bf16)v;
      hnode[row * 96 + c] = v;
    }
  }
  __syncthreads();
  {
    bf16x8 af[3];
#pragma unroll
    for (int kf = 0; kf < 3; kf++)
      af[kf] = *(const bf16x8*)&cnb[l16][kf * 32 + quad * 8];
    f32x4 accn = {0.f, 0.f, 0.f, 0.f};
#pragma unroll
    for (int kf = 0; kf < 3; kf++) {
      bf16x8 bfrag = *(const bf16x8*)&OW1[((wv * 3 + kf) * 64 + ln) * 8];
      accn = mfma_bf16(af[kf], bfrag, accn);
    }
    int col = wv * 16 + l16;
    float bias = ob1[col];
#pragma unroll
    for (int rr = 0; rr < 4; rr++) {
      float vv = accn[rr] + bias;
      s1b[quad * 4 + rr][col] = (bf16)(vv > 0.f ? vv : 0.f);
    }
  }
  __syncthreads();
  {
    bf16x8 af[2];
#pragma unroll
    for (int kf = 0; kf < 2; kf++)
      af[kf] = *(const bf16x8*)&s1b[l16][kf * 32 + quad * 8];
    f32x4 accn = {0.f, 0.f, 0.f, 0.f};
#pragma unroll
    for (int kf = 0; kf < 2; kf++) {
      bf16x8 bfrag = *(const bf16x8*)&OW2[((wv * 2 + kf) * 64 + ln) * 8];
      accn = mfma_bf16(af[kf], bfrag, accn);
    }
    int col = wv * 16 + l16;
    float bias = ob2[col];
#pragma unroll
    for (int rr = 0; rr < 4; rr++) {
      float vv = accn[rr] + bias;
      s2b[quad * 4 + rr][col] = (bf16)(vv > 0.f ? vv : 0.f);
    }
  }
  __syncthreads();
  if (wv < 2) {
    bf16x8 af[2];
#pragma unroll
    for (int kf = 0; kf < 2; kf++)
      af[kf] = *(const bf16x8*)&s2b[l16][kf * 32 + quad * 8];
    f32x4 accn = {0.f, 0.f, 0.f, 0.f};
#pragma unroll
    for (int kf = 0; kf < 2; kf++) {
      bf16x8 bfrag = *(const bf16x8*)&OW3[((wv * 2 + kf) * 64 + ln) * 8];
      accn = mfma_bf16(af[kf], bfrag, accn);
    }
    int d = wv * 16 + l16;
    float bias = ob3[d];
#pragma unroll
    for (int rr = 0; rr < 4; rr++) {
      int r = quad * 4 + rr;
      int b = q * 16 + r;
      float xm = xinf[r][d] + accn[rr] + bias;
      int base = (b * 32 + n) * 32 + d;
      out[524288 + base * 16 + t] = xm;
      out[1572864 + base * 16 + t] = xm;
      if (t >= NSTEP) out[base * 8 + (t - NSTEP)] = xm;
      float vnext = (t + 1 < NSTEP) ? x[base * 8 + (t + 1)] : xm;
      xf[n * 2048 + b * 32 + d] = vnext;
      xnb[r][d] = (bf16)vnext;
    }
  }
  __syncthreads();
  // Pcur epilogue: P for next step's edge_full (only needed when t+1 >= 8).
  // xnb has 16 rows shared by all waves; nt split across waves is complete.
  if (t + 1 >= NSTEP && t + 1 < NTT) {
    bf16x8 a = *(const bf16x8*)&xnb[l16][quad * 8];
#pragma unroll
    for (int s = 0; s < 6; s++) {
      int nt = wv * 6 + s;
      bf16x8 bfr = *(const bf16x8*)&W1P[(nt * 64 + ln) * 8];
      f32x4 c = {0.f, 0.f, 0.f, 0.f};
      c = mfma_bf16(a, bfr, c);
#pragma unroll
      for (int rr = 0; rr < 4; rr++)
        Pcur[(size_t)(n * 64 + q * 16 + quad * 4 + rr) * 384 + nt * 16 + l16] = c[rr];
    }
  }
}

extern "C" void kernel_launch(void* const* d_in, const int* in_sizes, int n_in,
                              void* d_out, int out_size, void* d_ws, size_t ws_size,
                              hipStream_t stream) {
  const float* x     = (const float*)d_in[0];
  const float* z     = (const float*)d_in[1];
  const int*   es    = (const int*)d_in[2];
  const float* msgW1 = (const float*)d_in[6];
  const float* msgb1 = (const float*)d_in[7];
  const float* msgW2 = (const float*)d_in[8];
  const float* msgb2 = (const float*)d_in[9];
  const float* oW1   = (const float*)d_in[10];
  const float* ob1   = (const float*)d_in[11];
  const float* oW2   = (const float*)d_in[12];
  const float* ob2   = (const float*)d_in[13];
  const float* oW3   = (const float*)d_in[14];
  const float* ob3   = (const float*)d_in[15];
  const float* geWi  = (const float*)d_in[16];
  const float* gebi  = (const float*)d_in[17];
  const float* geWh  = (const float*)d_in[18];
  const float* gebh  = (const float*)d_in[19];
  const float* gnWi  = (const float*)d_in[20];
  const float* gnbi  = (const float*)d_in[21];
  const float* gnWh  = (const float*)d_in[22];
  const float* gnbh  = (const float*)d_in[23];
  float* out = (float*)d_out;

  char* p = (char*)d_ws;
  bf16*  hed   = (bf16*)p;   p += (size_t)NE * 4096 * 2;          // 8.1 MB
  bf16*  mixbuf= (bf16*)p;   p += (size_t)7 * NE * 4096 * 2;      // 56.9 MB
  float* Pbuf  = (float*)p;  p += (size_t)8 * 32 * 64 * 384 * 4;  // 25.2 MB
  float* Pcur  = (float*)p;  p += (size_t)32 * 64 * 384 * 4;      // 3.1 MB
  float* xf    = (float*)p;  p += 65536 * 4;
  float* hnode = (float*)p;  p += 196608 * 4;
  bf16*  W1Psw = (bf16*)p;   p += 12288 * 2;
  bf16*  B2sw  = (bf16*)p;   p += 12288 * 2;
  bf16*  GIsw  = (bf16*)p;   p += 12288 * 2;
  bf16*  GHsw  = (bf16*)p;   p += 12288 * 2;
  bf16*  GNsw  = (bf16*)p;   p += 55296 * 2;
  bf16*  OW1s  = (bf16*)p;   p += 6144 * 2;
  bf16*  OW2s  = (bf16*)p;   p += 4096 * 2;
  bf16*  OW3s  = (bf16*)p;   p += 2048 * 2;

  prep_weights<<<204, 256, 0, stream>>>(msgW1, msgW2, geWi, geWh, gnWi, gnWh,
                                        oW1, oW2, oW3,
                                        W1Psw, B2sw, GIsw, GHsw, GNsw,
                                        OW1s, OW2s, OW3s);
  copy_x0<<<256, 256, 0, stream>>>(x, xf);
  p8_kernel<<<256, 256, 0, stream>>>(x, W1Psw, Pbuf);
  mix8_kernel<<<8 * 496, 256, 0, stream>>>(Pbuf, es, z, B2sw, msgb1, msgb2,
                                           hed, mixbuf);
  node_kernel<<<128, 256, 0, stream>>>(x, hed, xf, hnode, GNsw, gnbi, gnbh,
                                       OW1s, ob1, OW2s, ob2, OW3s, ob3,
                                       W1Psw, Pcur, out, 0);
  for (int t = 1; t < NSTEP; t++) {
    gru_step<<<496, 256, 0, stream>>>(mixbuf, hed, GIsw, GHsw, gebi, gebh, t);
    node_kernel<<<128, 256, 0, stream>>>(x, hed, xf, hnode, GNsw, gnbi, gnbh,
                                         OW1s, ob1, OW2s, ob2, OW3s, ob3,
                                         W1Psw, Pcur, out, t);
  }
  for (int t = NSTEP; t < NTT; t++) {
    edge_full<<<496, 256, 0, stream>>>(Pcur, es, z, B2sw, msgb1, msgb2,
                                       GIsw, GHsw, gebi, gebh, hed);
    node_kernel<<<128, 256, 0, stream>>>(x, hed, xf, hnode, GNsw, gnbi, gnbh,
                                         OW1s, ob1, OW2s, ob2, OW3s, ob3,
                                         W1Psw, Pcur, out, t);
  }
}

// Round 11
// 829.418 us; speedup vs baseline: 1.0220x; 1.0220x over previous
//
#include <hip/hip_runtime.h>
#include <hip/hip_bf16.h>

// Problem dims
#define NNODE 32
#define NB    64
#define NDIM  32
#define NSTEP 8
#define NE    992
#define NTT   16

typedef __bf16 bf16;
typedef __attribute__((ext_vector_type(8))) __bf16 bf16x8;
typedef __attribute__((ext_vector_type(4))) __bf16 bf16x4;
typedef __attribute__((ext_vector_type(4))) float  f32x4;

__device__ __forceinline__ f32x4 mfma_bf16(bf16x8 a, bf16x8 b, f32x4 c) {
  return __builtin_amdgcn_mfma_f32_16x16x32_bf16(a, b, c, 0, 0, 0);
}
__device__ __forceinline__ float sigm(float x) { return 1.0f / (1.0f + __expf(-x)); }
__device__ __forceinline__ float tanh_f(float x) {
  x = fminf(fmaxf(x, -15.0f), 15.0f);
  float e = __expf(2.0f * x);
  return (e - 1.0f) / (e + 1.0f);
}

// ---------------------------------------------------------------------------
// Weight swizzles. B-frag (K=64): slot ((nt*KF+kf)*64+lane)*8+j holds
// B[kf*32+(lane>>4)*8+j][nt*16+(lane&15)].
// W1P (K=32): msg@W1 split into x_row@W1_top (nt 0..11) | x_col@W1_bot (12..23).
// ---------------------------------------------------------------------------
__global__ void prep_weights(
    const float* __restrict__ msgW1, const float* __restrict__ msgW2,
    const float* __restrict__ geWi,  const float* __restrict__ geWh,
    const float* __restrict__ gnWi,  const float* __restrict__ gnWh,
    const float* __restrict__ oW1,   const float* __restrict__ oW2,
    const float* __restrict__ oW3,
    bf16* __restrict__ W1P, bf16* __restrict__ B2,
    bf16* __restrict__ GI, bf16* __restrict__ GH,
    bf16* __restrict__ GN,
    bf16* __restrict__ OW1s, bf16* __restrict__ OW2s, bf16* __restrict__ OW3s) {
  int u = blockIdx.x * 256 + threadIdx.x;
  if (u < 12288) {
    int k = u >> 12, i = (u >> 6) & 63, h = u & 63;
    int kf = i >> 5, quad = (i >> 3) & 3, j = i & 7;
    int nn = k * 64 + h, nt = nn >> 4, lane = quad * 16 + (nn & 15);
    int slot = ((nt * 2 + kf) * 64 + lane) * 8 + j;
    GI[slot] = (bf16)geWi[u];
    GH[slot] = (bf16)geWh[u];
    int ntl = h >> 4, lane2 = quad * 16 + (h & 15);
    int slot2 = k * 4096 + ((ntl * 2 + kf) * 64 + lane2) * 8 + j;
    B2[slot2] = (bf16)msgW2[u];
    // W1P: K=32 frag; nt3 = kf*12 + (n>>4)
    int loc = i & 31, q3 = loc >> 3, j3 = loc & 7;
    int nt3 = kf * 12 + (nn >> 4);
    int lane3 = q3 * 16 + (nn & 15);
    W1P[(nt3 * 64 + lane3) * 8 + j3] = (bf16)msgW1[u];
  } else if (u < 39936) {
    int v = u - 12288;
    int kk = v / 9216, rem = v % 9216, i = rem / 96, h = rem % 96;
    int kf = i >> 5, loc = i & 31, quad = loc >> 3, j = loc & 7;
    int nn = kk * 96 + h, nt = nn >> 4, lane = quad * 16 + (nn & 15);
    int slot = ((nt * 3 + kf) * 64 + lane) * 8 + j;
    GN[slot]         = (bf16)gnWi[v];
    GN[27648 + slot] = (bf16)gnWh[v];
  } else if (u < 46080) {
    int v = u - 39936; int i = v >> 6, h = v & 63;
    int kf = i >> 5, loc = i & 31, quad = loc >> 3, j = loc & 7;
    int nt = h >> 4, lane = quad * 16 + (h & 15);
    OW1s[((nt * 3 + kf) * 64 + lane) * 8 + j] = (bf16)oW1[v];
  } else if (u < 50176) {
    int v = u - 46080; int i = v >> 6, h = v & 63;
    int kf = i >> 5, quad = (i >> 3) & 3, j = i & 7;
    int nt = h >> 4, lane = quad * 16 + (h & 15);
    OW2s[((nt * 2 + kf) * 64 + lane) * 8 + j] = (bf16)oW2[v];
  } else if (u < 52224) {
    int v = u - 50176; int i = v >> 5, h = v & 31;
    int kf = i >> 5, quad = (i >> 3) & 3, j = i & 7;
    int nt = h >> 4, lane = quad * 16 + (h & 15);
    OW3s[((nt * 2 + kf) * 64 + lane) * 8 + j] = (bf16)oW3[v];
  }
}

// t=0 input into xf (fp32), layout [n][b][d].
__global__ void copy_x0(const float* __restrict__ x, float* __restrict__ xf) {
  int u = blockIdx.x * 256 + threadIdx.x;  // 65536
  int n = u >> 11, b = (u >> 5) & 63, d = u & 31;
  xf[u] = x[((b * 32 + n) * 32 + d) * 8 + 0];
}

// ---------------------------------------------------------------------------
// P precompute for ground-truth steps: P[t][n][b][0..383] (P1 | P2), FP32.
// Grid 256 blocks = 8t x 32n. Each wave: its 16-batch block x ALL 24 nt.
// ---------------------------------------------------------------------------
__global__ __launch_bounds__(256) void p8_kernel(
    const float* __restrict__ x, const bf16* __restrict__ W1P,
    float* __restrict__ Pbuf) {
  __shared__ __align__(16) bf16 XA[64][40];
  int t = blockIdx.x >> 5, n = blockIdx.x & 31;
  int tid = threadIdx.x;
  for (int u = tid; u < 2048; u += 256) {
    int b = u >> 5, d = u & 31;
    XA[b][d] = (bf16)x[((b * 32 + n) * 32 + d) * 8 + t];
  }
  __syncthreads();
  int wv = tid >> 6, ln = tid & 63, quad = ln >> 4, l16 = ln & 15;
  bf16x8 a = *(const bf16x8*)&XA[wv * 16 + l16][quad * 8];
  float* Pt = Pbuf + ((size_t)(t * 32 + n) * 64) * 384;
#pragma unroll
  for (int nt = 0; nt < 24; nt++) {
    bf16x8 bfr = *(const bf16x8*)&W1P[(nt * 64 + ln) * 8];
    f32x4 c = {0.f, 0.f, 0.f, 0.f};
    c = mfma_bf16(a, bfr, c);
#pragma unroll
    for (int rr = 0; rr < 4; rr++)
      Pt[(size_t)(wv * 16 + quad * 4 + rr) * 384 + nt * 16 + l16] = c[rr];
  }
}

// build layer-2 A-fragment chunk from fp32 P halves + bias, relu, bf16
__device__ __forceinline__ bf16x8 mk_h1(const float* b1p, const float* b2p,
                                        const float* biasL, int col) {
  f32x4 pa0 = *(const f32x4*)(b1p + col);
  f32x4 pa1 = *(const f32x4*)(b1p + col + 4);
  f32x4 pb0 = *(const f32x4*)(b2p + col);
  f32x4 pb1 = *(const f32x4*)(b2p + col + 4);
  bf16x8 h;
#pragma unroll
  for (int j = 0; j < 4; j++) {
    float v0 = pa0[j] + pb0[j] + biasL[col + j];
    float v1 = pa1[j] + pb1[j] + biasL[col + 4 + j];
    h[j]     = (bf16)(v0 > 0.f ? v0 : 0.f);
    h[4 + j] = (bf16)(v1 > 0.f ? v1 : 0.f);
  }
  return h;
}

// ---------------------------------------------------------------------------
// Unified edge step (all 16 t's): layer2 from P (fp32) + z-mix; if do_gru,
// GRU update against hed; else hed = mix. 496 blocks (2 edges each).
// ---------------------------------------------------------------------------
__global__ __launch_bounds__(256, 2) void edge_step(
    const float* __restrict__ P, const int* __restrict__ es,
    const float* __restrict__ z,
    const bf16* __restrict__ B2,
    const float* __restrict__ mb1, const float* __restrict__ mb2,
    const bf16* __restrict__ GI, const bf16* __restrict__ GH,
    const float* __restrict__ gbi, const float* __restrict__ gbh,
    bf16* __restrict__ hed, int do_gru) {
  __shared__ __align__(16) bf16 S[2][64][72];   // mix, then new state
  __shared__ float zL[2][64][3];
  __shared__ float biasL[768];  // mb1 | mb2 | gbi | gbh
  int e0 = blockIdx.x * 2, tid = threadIdx.x;
  int cn0 = es[e0], rn0 = es[NE + e0];
  int cn1 = es[e0 + 1], rn1 = es[NE + e0 + 1];
  for (int u = tid; u < 768; u += 256)
    biasL[u] = (u < 192) ? mb1[u] : (u < 384) ? mb2[u - 192]
             : (u < 576) ? gbi[u - 384] : gbh[u - 576];
  for (int u = tid; u < 384; u += 256) {
    int pe = u / 192, rem = u % 192, b = rem / 3, k = rem % 3;
    zL[pe][b][k] = z[(b * NE + e0 + pe) * 3 + k];
  }
  __syncthreads();
  int wv = tid >> 6, ln = tid & 63, quad = ln >> 4, l16 = ln & 15;
  int m = wv * 16 + l16;
  bf16x8 a2[2][3][2];
#pragma unroll
  for (int pe = 0; pe < 2; pe++) {
    int rn = pe ? rn1 : rn0, cnn = pe ? cn1 : cn0;
    const float* b1p = P + ((size_t)rn * 64 + m) * 384;
    const float* b2p = P + ((size_t)cnn * 64 + m) * 384 + 192;
#pragma unroll
    for (int kt = 0; kt < 3; kt++)
#pragma unroll
      for (int kf = 0; kf < 2; kf++)
        a2[pe][kt][kf] = mk_h1(b1p, b2p, biasL, kt * 64 + kf * 32 + quad * 8);
  }
  f32x4 acc2[2][12];
#pragma unroll
  for (int pe = 0; pe < 2; pe++)
#pragma unroll
    for (int q = 0; q < 12; q++) { f32x4 zz = {0.f,0.f,0.f,0.f}; acc2[pe][q] = zz; }
#pragma unroll
  for (int kt = 0; kt < 3; kt++)
#pragma unroll
    for (int nt = 0; nt < 4; nt++) {
      bf16x8 w0 = *(const bf16x8*)&B2[kt * 4096 + (nt * 2 + 0) * 512 + ln * 8];
      bf16x8 w1 = *(const bf16x8*)&B2[kt * 4096 + (nt * 2 + 1) * 512 + ln * 8];
#pragma unroll
      for (int pe = 0; pe < 2; pe++) {
        acc2[pe][kt * 4 + nt] = mfma_bf16(a2[pe][kt][0], w0, acc2[pe][kt * 4 + nt]);
        acc2[pe][kt * 4 + nt] = mfma_bf16(a2[pe][kt][1], w1, acc2[pe][kt * 4 + nt]);
      }
    }
  // mix -> LDS S (own-wave rows)
#pragma unroll
  for (int pe = 0; pe < 2; pe++)
#pragma unroll
    for (int r = 0; r < 4; r++) {
      int b = wv * 16 + quad * 4 + r;
      float z0 = zL[pe][b][0], z1 = zL[pe][b][1], z2 = zL[pe][b][2];
#pragma unroll
      for (int nt = 0; nt < 4; nt++) {
        int o = nt * 16 + l16;
        float h0 = acc2[pe][nt][r]     + biasL[192 + o];       h0 = h0 > 0.f ? h0 : 0.f;
        float h1 = acc2[pe][4 + nt][r] + biasL[192 + 64 + o];  h1 = h1 > 0.f ? h1 : 0.f;
        float h2 = acc2[pe][8 + nt][r] + biasL[192 + 128 + o]; h2 = h2 > 0.f ? h2 : 0.f;
        S[pe][b][o] = (bf16)((h0 * z0 + h1 * z1 + h2 * z2) * (1.0f / 3.0f));
      }
    }
  if (do_gru) {
    __syncthreads();
    bf16x8 ai[2][2], ah[2][2];
#pragma unroll
    for (int pe = 0; pe < 2; pe++) {
      const bf16* hrow = hed + (size_t)(e0 + pe) * 4096 + m * 64;
#pragma unroll
      for (int kf = 0; kf < 2; kf++) {
        ai[pe][kf] = *(const bf16x8*)&S[pe][m][kf * 32 + quad * 8];
        ah[pe][kf] = *(const bf16x8*)(hrow + kf * 32 + quad * 8);
      }
    }
    f32x4 gri[2][8], gni[2][4], gnh[2][4];
#pragma unroll
    for (int pe = 0; pe < 2; pe++) {
#pragma unroll
      for (int q = 0; q < 8; q++) { f32x4 zz = {0.f,0.f,0.f,0.f}; gri[pe][q] = zz; }
#pragma unroll
      for (int q = 0; q < 4; q++) { f32x4 zz = {0.f,0.f,0.f,0.f}; gni[pe][q] = zz; gnh[pe][q] = zz; }
    }
#pragma unroll
    for (int nt = 0; nt < 8; nt++) {
      bf16x8 wi0 = *(const bf16x8*)&GI[(nt * 2 + 0) * 512 + ln * 8];
      bf16x8 wi1 = *(const bf16x8*)&GI[(nt * 2 + 1) * 512 + ln * 8];
      bf16x8 wh0 = *(const bf16x8*)&GH[(nt * 2 + 0) * 512 + ln * 8];
      bf16x8 wh1 = *(const bf16x8*)&GH[(nt * 2 + 1) * 512 + ln * 8];
#pragma unroll
      for (int pe = 0; pe < 2; pe++) {
        gri[pe][nt] = mfma_bf16(ai[pe][0], wi0, gri[pe][nt]);
        gri[pe][nt] = mfma_bf16(ai[pe][1], wi1, gri[pe][nt]);
        gri[pe][nt] = mfma_bf16(ah[pe][0], wh0, gri[pe][nt]);
        gri[pe][nt] = mfma_bf16(ah[pe][1], wh1, gri[pe][nt]);
      }
    }
#pragma unroll
    for (int nt = 8; nt < 12; nt++) {
      bf16x8 wi0 = *(const bf16x8*)&GI[(nt * 2 + 0) * 512 + ln * 8];
      bf16x8 wi1 = *(const bf16x8*)&GI[(nt * 2 + 1) * 512 + ln * 8];
      bf16x8 wh0 = *(const bf16x8*)&GH[(nt * 2 + 0) * 512 + ln * 8];
      bf16x8 wh1 = *(const bf16x8*)&GH[(nt * 2 + 1) * 512 + ln * 8];
#pragma unroll
      for (int pe = 0; pe < 2; pe++) {
        gni[pe][nt - 8] = mfma_bf16(ai[pe][0], wi0, gni[pe][nt - 8]);
        gni[pe][nt - 8] = mfma_bf16(ai[pe][1], wi1, gni[pe][nt - 8]);
        gnh[pe][nt - 8] = mfma_bf16(ah[pe][0], wh0, gnh[pe][nt - 8]);
        gnh[pe][nt - 8] = mfma_bf16(ah[pe][1], wh1, gnh[pe][nt - 8]);
      }
    }
#pragma unroll
    for (int pe = 0; pe < 2; pe++)
#pragma unroll
      for (int r = 0; r < 4; r++) {
        int b = wv * 16 + quad * 4 + r;
#pragma unroll
        for (int nt = 0; nt < 4; nt++) {
          int o = nt * 16 + l16;
          float xr = gri[pe][nt][r]     + biasL[384 + o]      + biasL[576 + o];
          float xi = gri[pe][4 + nt][r] + biasL[384 + 64 + o] + biasL[576 + 64 + o];
          float xn = gni[pe][nt][r] + biasL[384 + 128 + o];
          float hn = gnh[pe][nt][r] + biasL[576 + 128 + o];
          float rg = sigm(xr);
          float ig = sigm(xi);
          float ng = tanh_f(xn + rg * hn);
          float hv = (float)hed[(size_t)(e0 + pe) * 4096 + b * 64 + o];
          S[pe][b][o] = (bf16)((1.0f - ig) * ng + ig * hv);
        }
      }
  }
  __syncthreads();
  for (int u = tid; u < 1024; u += 256) {
    int pe = u >> 9, c = u & 511, b = c >> 3, j = c & 7;
    *(bf16x8*)(hed + (size_t)(e0 + pe) * 4096 + b * 64 + j * 8) = *(const bf16x8*)&S[pe][b][j * 8];
  }
}

// ---------------------------------------------------------------------------
// Node kernel: agg + node GRU (MFMA) + out-MLP + next-input + Pcur epilogue.
// 128 blocks.
// ---------------------------------------------------------------------------
__global__ __launch_bounds__(256) void node_kernel(
    const float* __restrict__ x, const bf16* __restrict__ hed,
    float* __restrict__ xf, float* __restrict__ hnode,
    const bf16* __restrict__ GN,
    const float* __restrict__ gnbi, const float* __restrict__ gnbh,
    const bf16* __restrict__ OW1, const float* __restrict__ ob1,
    const bf16* __restrict__ OW2, const float* __restrict__ ob2,
    const bf16* __restrict__ OW3, const float* __restrict__ ob3,
    const bf16* __restrict__ W1P, float* __restrict__ Pcur,
    float* __restrict__ out, int t) {
  __shared__ float aggf[16][64];
  __shared__ float xinf[16][32];
  __shared__ float hvf[16][96];
  __shared__ __align__(16) bf16 c0b[16][112];
  __shared__ __align__(16) bf16 hvb[16][112];
  __shared__ float gsum[2][16][290];
  __shared__ __align__(16) bf16 cnb[16][112];
  __shared__ __align__(16) bf16 s1b[16][112];
  __shared__ __align__(16) bf16 s2b[16][112];
  __shared__ __align__(16) bf16 xnb[16][40];
  int nq = blockIdx.x, n = nq >> 2, q = nq & 3;
  int tid = threadIdx.x;
  {
    int r = tid >> 4, o4 = tid & 15;
    const bf16x4* bp = (const bf16x4*)hed + (size_t)n * 31 * 1024 + (q * 16 + r) * 16 + o4;
    float sx = 0.f, sy = 0.f, sz = 0.f, sw = 0.f;
#pragma unroll
    for (int e2 = 0; e2 < 31; e2++) {
      bf16x4 v = bp[e2 * 1024];
      sx += (float)v[0]; sy += (float)v[1]; sz += (float)v[2]; sw += (float)v[3];
    }
    const float inv = 1.0f / 31.0f;
    sx *= inv; sy *= inv; sz *= inv; sw *= inv;
    int o = o4 * 4;
    aggf[r][o] = sx; aggf[r][o + 1] = sy; aggf[r][o + 2] = sz; aggf[r][o + 3] = sw;
    c0b[r][32 + o] = (bf16)sx; c0b[r][33 + o] = (bf16)sy;
    c0b[r][34 + o] = (bf16)sz; c0b[r][35 + o] = (bf16)sw;
  }
  if (tid < 128) {
    int r = tid >> 3, d0 = (tid & 7) * 4;
    int b = q * 16 + r;
#pragma unroll
    for (int k = 0; k < 4; k++) {
      float v = xf[n * 2048 + b * 32 + d0 + k];
      xinf[r][d0 + k] = v;
      c0b[r][d0 + k] = (bf16)v;
    }
  }
  if (t > 0) {
    int r = tid >> 4, cb = (tid & 15) * 6;
    int row = n * 64 + q * 16 + r;
#pragma unroll
    for (int k = 0; k < 6; k++) {
      float v = hnode[row * 96 + cb + k];
      hvf[r][cb + k] = v;
      hvb[r][cb + k] = (bf16)v;
    }
  }
  __syncthreads();
  int wv = tid >> 6, ln = tid & 63, quad = ln >> 4, l16 = ln & 15;
  if (t > 0) {
    int mat = wv >> 1, sel = wv & 1;
    const bf16(*Ab)[112] = mat ? hvb : c0b;
    bf16x8 af[3];
#pragma unroll
    for (int kf = 0; kf < 3; kf++)
      af[kf] = *(const bf16x8*)&Ab[l16][kf * 32 + quad * 8];
    const bf16* W = GN + mat * 27648;
    f32x4 accn[9];
#pragma unroll
    for (int q2 = 0; q2 < 9; q2++) { f32x4 zz = {0.f,0.f,0.f,0.f}; accn[q2] = zz; }
#pragma unroll
    for (int nt2 = 0; nt2 < 9; nt2++) {
      int nt = sel * 9 + nt2;
#pragma unroll
      for (int kf = 0; kf < 3; kf++) {
        bf16x8 bfrag = *(const bf16x8*)&W[((nt * 3 + kf) * 64 + ln) * 8];
        accn[nt2] = mfma_bf16(af[kf], bfrag, accn[nt2]);
      }
    }
#pragma unroll
    for (int nt2 = 0; nt2 < 9; nt2++) {
      int col = (sel * 9 + nt2) * 16 + l16;
#pragma unroll
      for (int rr = 0; rr < 4; rr++)
        gsum[mat][quad * 4 + rr][col] = accn[nt2][rr];
    }
  }
  __syncthreads();
  {
    int r = tid >> 4, cb = (tid & 15) * 6;
    int row = n * 64 + q * 16 + r;
#pragma unroll
    for (int k = 0; k < 6; k++) {
      int c = cb + k;
      float v;
      if (t > 0) {
        float xr = gsum[0][r][c] + gnbi[c] + gsum[1][r][c] + gnbh[c];
        float xi = gsum[0][r][96 + c] + gnbi[96 + c] + gsum[1][r][96 + c] + gnbh[96 + c];
        float xn = gsum[0][r][192 + c] + gnbi[192 + c];
        float hn = gsum[1][r][192 + c] + gnbh[192 + c];
        float rg = sigm(xr);
        float ig = sigm(xi);
        float ng = tanh_f(xn + rg * hn);
        v = (1.0f - ig) * ng + ig * hvf[r][c];
      } else {
        v = (c < 32) ? xinf[r][c] : aggf[r][c - 32];
      }
      cnb[r][c] = (bf16)v;
      hnode[row * 96 + c] = v;
    }
  }
  __syncthreads();
  {
    bf16x8 af[3];
#pragma unroll
    for (int kf = 0; kf < 3; kf++)
      af[kf] = *(const bf16x8*)&cnb[l16][kf * 32 + quad * 8];
    f32x4 accn = {0.f, 0.f, 0.f, 0.f};
#pragma unroll
    for (int kf = 0; kf < 3; kf++) {
      bf16x8 bfrag = *(const bf16x8*)&OW1[((wv * 3 + kf) * 64 + ln) * 8];
      accn = mfma_bf16(af[kf], bfrag, accn);
    }
    int col = wv * 16 + l16;
    float bias = ob1[col];
#pragma unroll
    for (int rr = 0; rr < 4; rr++) {
      float vv = accn[rr] + bias;
      s1b[quad * 4 + rr][col] = (bf16)(vv > 0.f ? vv : 0.f);
    }
  }
  __syncthreads();
  {
    bf16x8 af[2];
#pragma unroll
    for (int kf = 0; kf < 2; kf++)
      af[kf] = *(const bf16x8*)&s1b[l16][kf * 32 + quad * 8];
    f32x4 accn = {0.f, 0.f, 0.f, 0.f};
#pragma unroll
    for (int kf = 0; kf < 2; kf++) {
      bf16x8 bfrag = *(const bf16x8*)&OW2[((wv * 2 + kf) * 64 + ln) * 8];
      accn = mfma_bf16(af[kf], bfrag, accn);
    }
    int col = wv * 16 + l16;
    float bias = ob2[col];
#pragma unroll
    for (int rr = 0; rr < 4; rr++) {
      float vv = accn[rr] + bias;
      s2b[quad * 4 + rr][col] = (bf16)(vv > 0.f ? vv : 0.f);
    }
  }
  __syncthreads();
  if (wv < 2) {
    bf16x8 af[2];
#pragma unroll
    for (int kf = 0; kf < 2; kf++)
      af[kf] = *(const bf16x8*)&s2b[l16][kf * 32 + quad * 8];
    f32x4 accn = {0.f, 0.f, 0.f, 0.f};
#pragma unroll
    for (int kf = 0; kf < 2; kf++) {
      bf16x8 bfrag = *(const bf16x8*)&OW3[((wv * 2 + kf) * 64 + ln) * 8];
      accn = mfma_bf16(af[kf], bfrag, accn);
    }
    int d = wv * 16 + l16;
    float bias = ob3[d];
#pragma unroll
    for (int rr = 0; rr < 4; rr++) {
      int r = quad * 4 + rr;
      int b = q * 16 + r;
      float xm = xinf[r][d] + accn[rr] + bias;
      int base = (b * 32 + n) * 32 + d;
      out[524288 + base * 16 + t] = xm;
      out[1572864 + base * 16 + t] = xm;
      if (t >= NSTEP) out[base * 8 + (t - NSTEP)] = xm;
      float vnext = (t + 1 < NSTEP) ? x[base * 8 + (t + 1)] : xm;
      xf[n * 2048 + b * 32 + d] = vnext;
      xnb[r][d] = (bf16)vnext;
    }
  }
  __syncthreads();
  // Pcur epilogue: P for next step's edge_step (only needed when t+1 >= 8).
  if (t + 1 >= NSTEP && t + 1 < NTT) {
    bf16x8 a = *(const bf16x8*)&xnb[l16][quad * 8];
#pragma unroll
    for (int s = 0; s < 6; s++) {
      int nt = wv * 6 + s;
      bf16x8 bfr = *(const bf16x8*)&W1P[(nt * 64 + ln) * 8];
      f32x4 c = {0.f, 0.f, 0.f, 0.f};
      c = mfma_bf16(a, bfr, c);
#pragma unroll
      for (int rr = 0; rr < 4; rr++)
        Pcur[(size_t)(n * 64 + q * 16 + quad * 4 + rr) * 384 + nt * 16 + l16] = c[rr];
    }
  }
}

extern "C" void kernel_launch(void* const* d_in, const int* in_sizes, int n_in,
                              void* d_out, int out_size, void* d_ws, size_t ws_size,
                              hipStream_t stream) {
  const float* x     = (const float*)d_in[0];
  const float* z     = (const float*)d_in[1];
  const int*   es    = (const int*)d_in[2];
  const float* msgW1 = (const float*)d_in[6];
  const float* msgb1 = (const float*)d_in[7];
  const float* msgW2 = (const float*)d_in[8];
  const float* msgb2 = (const float*)d_in[9];
  const float* oW1   = (const float*)d_in[10];
  const float* ob1   = (const float*)d_in[11];
  const float* oW2   = (const float*)d_in[12];
  const float* ob2   = (const float*)d_in[13];
  const float* oW3   = (const float*)d_in[14];
  const float* ob3   = (const float*)d_in[15];
  const float* geWi  = (const float*)d_in[16];
  const float* gebi  = (const float*)d_in[17];
  const float* geWh  = (const float*)d_in[18];
  const float* gebh  = (const float*)d_in[19];
  const float* gnWi  = (const float*)d_in[20];
  const float* gnbi  = (const float*)d_in[21];
  const float* gnWh  = (const float*)d_in[22];
  const float* gnbh  = (const float*)d_in[23];
  float* out = (float*)d_out;

  char* p = (char*)d_ws;
  bf16*  hed   = (bf16*)p;   p += (size_t)NE * 4096 * 2;          // 8.1 MB
  float* Pbuf  = (float*)p;  p += (size_t)8 * 32 * 64 * 384 * 4;  // 25.2 MB
  float* Pcur  = (float*)p;  p += (size_t)32 * 64 * 384 * 4;      // 3.1 MB
  float* xf    = (float*)p;  p += 65536 * 4;
  float* hnode = (float*)p;  p += 196608 * 4;
  bf16*  W1Psw = (bf16*)p;   p += 12288 * 2;
  bf16*  B2sw  = (bf16*)p;   p += 12288 * 2;
  bf16*  GIsw  = (bf16*)p;   p += 12288 * 2;
  bf16*  GHsw  = (bf16*)p;   p += 12288 * 2;
  bf16*  GNsw  = (bf16*)p;   p += 55296 * 2;
  bf16*  OW1s  = (bf16*)p;   p += 6144 * 2;
  bf16*  OW2s  = (bf16*)p;   p += 4096 * 2;
  bf16*  OW3s  = (bf16*)p;   p += 2048 * 2;

  prep_weights<<<204, 256, 0, stream>>>(msgW1, msgW2, geWi, geWh, gnWi, gnWh,
                                        oW1, oW2, oW3,
                                        W1Psw, B2sw, GIsw, GHsw, GNsw,
                                        OW1s, OW2s, OW3s);
  copy_x0<<<256, 256, 0, stream>>>(x, xf);
  p8_kernel<<<256, 256, 0, stream>>>(x, W1Psw, Pbuf);

  for (int t = 0; t < NTT; t++) {
    const float* Pt = (t < NSTEP) ? (Pbuf + (size_t)t * 32 * 64 * 384) : Pcur;
    edge_step<<<496, 256, 0, stream>>>(Pt, es, z, B2sw, msgb1, msgb2,
                                       GIsw, GHsw, gebi, gebh, hed, t > 0 ? 1 : 0);
    node_kernel<<<128, 256, 0, stream>>>(x, hed, xf, hnode, GNsw, gnbi, gnbh,
                                         OW1s, ob1, OW2s, ob2, OW3s, ob3,
                                         W1Psw, Pcur, out, t);
  }
}

// Round 12
// 680.504 us; speedup vs baseline: 1.2456x; 1.2188x over previous
//
#include <hip/hip_runtime.h>
#include <hip/hip_bf16.h>

// Problem dims
#define NNODE 32
#define NB    64
#define NDIM  32
#define NSTEP 8
#define NE    992
#define NTT   16

typedef __bf16 bf16;
typedef __attribute__((ext_vector_type(8))) __bf16 bf16x8;
typedef __attribute__((ext_vector_type(4))) __bf16 bf16x4;
typedef __attribute__((ext_vector_type(4))) float  f32x4;

__device__ __forceinline__ f32x4 mfma_bf16(bf16x8 a, bf16x8 b, f32x4 c) {
  return __builtin_amdgcn_mfma_f32_16x16x32_bf16(a, b, c, 0, 0, 0);
}
__device__ __forceinline__ float sigm(float x) { return 1.0f / (1.0f + __expf(-x)); }
__device__ __forceinline__ float tanh_f(float x) {
  x = fminf(fmaxf(x, -15.0f), 15.0f);
  float e = __expf(2.0f * x);
  return (e - 1.0f) / (e + 1.0f);
}

// ---------------------------------------------------------------------------
// Weight swizzle into MFMA B-fragment bf16 order (round-7 validated layouts).
// ---------------------------------------------------------------------------
__global__ void prep_weights(
    const float* __restrict__ msgW1, const float* __restrict__ msgW2,
    const float* __restrict__ geWi,  const float* __restrict__ geWh,
    const float* __restrict__ gnWi,  const float* __restrict__ gnWh,
    const float* __restrict__ oW1,   const float* __restrict__ oW2,
    const float* __restrict__ oW3,
    bf16* __restrict__ B1, bf16* __restrict__ B2,
    bf16* __restrict__ GI, bf16* __restrict__ GH,
    bf16* __restrict__ GN,
    bf16* __restrict__ OW1s, bf16* __restrict__ OW2s, bf16* __restrict__ OW3s) {
  int u = blockIdx.x * 256 + threadIdx.x;
  if (u < 12288) {
    int k = u >> 12, i = (u >> 6) & 63, h = u & 63;
    int kf = i >> 5, quad = (i >> 3) & 3, j = i & 7;
    int nn = k * 64 + h, nt = nn >> 4, lane = quad * 16 + (nn & 15);
    int slot = ((nt * 2 + kf) * 64 + lane) * 8 + j;
    B1[slot] = (bf16)msgW1[u];
    GI[slot] = (bf16)geWi[u];
    GH[slot] = (bf16)geWh[u];
    int ntl = h >> 4, lane2 = quad * 16 + (h & 15);
    int slot2 = k * 4096 + ((ntl * 2 + kf) * 64 + lane2) * 8 + j;
    B2[slot2] = (bf16)msgW2[u];
  } else if (u < 39936) {
    int v = u - 12288;
    int kk = v / 9216, rem = v % 9216, i = rem / 96, h = rem % 96;
    int kf = i >> 5, loc = i & 31, quad = loc >> 3, j = loc & 7;
    int nn = kk * 96 + h, nt = nn >> 4, lane = quad * 16 + (nn & 15);
    int slot = ((nt * 3 + kf) * 64 + lane) * 8 + j;
    GN[slot]         = (bf16)gnWi[v];
    GN[27648 + slot] = (bf16)gnWh[v];
  } else if (u < 46080) {
    int v = u - 39936; int i = v >> 6, h = v & 63;
    int kf = i >> 5, loc = i & 31, quad = loc >> 3, j = loc & 7;
    int nt = h >> 4, lane = quad * 16 + (h & 15);
    OW1s[((nt * 3 + kf) * 64 + lane) * 8 + j] = (bf16)oW1[v];
  } else if (u < 50176) {
    int v = u - 46080; int i = v >> 6, h = v & 63;
    int kf = i >> 5, quad = (i >> 3) & 3, j = i & 7;
    int nt = h >> 4, lane = quad * 16 + (h & 15);
    OW2s[((nt * 2 + kf) * 64 + lane) * 8 + j] = (bf16)oW2[v];
  } else if (u < 52224) {
    int v = u - 50176; int i = v >> 5, h = v & 31;
    int kf = i >> 5, quad = (i >> 3) & 3, j = i & 7;
    int nt = h >> 4, lane = quad * 16 + (h & 15);
    OW3s[((nt * 2 + kf) * 64 + lane) * 8 + j] = (bf16)oW3[v];
  }
}

// Pre-transpose ground truth: xall[t][n][b][d] bf16, t=0..7.
__global__ void copy_xall(const float* __restrict__ x, bf16* __restrict__ xall) {
  int u = blockIdx.x * 256 + threadIdx.x;  // 524288
  int t = u >> 16, rem = u & 65535;
  int n = rem >> 11, b = (rem >> 5) & 63, d = rem & 31;
  xall[u] = (bf16)x[((b * 32 + n) * 32 + d) * 8 + t];
}

// ---------------------------------------------------------------------------
// mix8x: msg-MLP mixture for all 8 ground-truth steps in ONE dispatch.
// Grid 8*496 (t x edge-pair). Writes mixall[t][e][b][o] bf16.
// ---------------------------------------------------------------------------
__global__ __launch_bounds__(256, 2) void mix8x(
    const bf16* __restrict__ xall, const int* __restrict__ es,
    const float* __restrict__ z,
    const bf16* __restrict__ B1, const bf16* __restrict__ B2,
    const float* __restrict__ mb1, const float* __restrict__ mb2,
    bf16* __restrict__ mixall) {
  __shared__ __align__(16) char scrbuf[51200];
  __shared__ float zL[2][64][3];
  __shared__ float biasL[384];  // mb1 | mb2
  bf16 (*A)[64][72]   = (bf16(*)[64][72])scrbuf;
  bf16 (*A2)[64][200] = (bf16(*)[64][200])scrbuf;
  bf16 (*S)[64][72]   = (bf16(*)[64][72])scrbuf;
  int t = blockIdx.x / 496, pair = blockIdx.x % 496;
  int e0 = pair * 2, tid = threadIdx.x;
  int cn0 = es[e0], rn0 = es[NE + e0];
  int cn1 = es[e0 + 1], rn1 = es[NE + e0 + 1];
  for (int u = tid; u < 384; u += 256)
    biasL[u] = (u < 192) ? mb1[u] : mb2[u - 192];
  for (int u = tid; u < 384; u += 256) {
    int pe = u / 192, rem = u % 192, b = rem / 3, k = rem % 3;
    zL[pe][b][k] = z[(b * NE + e0 + pe) * 3 + k];
  }
  const bf16* xt = xall + (size_t)t * 65536;
  for (int u = tid; u < 1024; u += 256) {
    int pe = u >> 9, c = u & 511, b = c >> 3, i8 = c & 7;
    int nrow = pe ? rn1 : rn0, ncol = pe ? cn1 : cn0;
    const bf16* src = (i8 < 4) ? (xt + nrow * 2048 + b * 32 + i8 * 8)
                               : (xt + ncol * 2048 + b * 32 + (i8 - 4) * 8);
    *(bf16x8*)&A[pe][b][i8 * 8] = *(const bf16x8*)src;
  }
  __syncthreads();
  int wv = tid >> 6, ln = tid & 63, quad = ln >> 4, l16 = ln & 15;
  int m = wv * 16 + l16;
  bf16x8 af[2][2];
#pragma unroll
  for (int pe = 0; pe < 2; pe++)
#pragma unroll
    for (int kf = 0; kf < 2; kf++)
      af[pe][kf] = *(const bf16x8*)&A[pe][m][kf * 32 + quad * 8];
  __syncthreads();  // A dead -> A2 may overwrite
  f32x4 acc[2][12];
#pragma unroll
  for (int pe = 0; pe < 2; pe++)
#pragma unroll
    for (int q = 0; q < 12; q++) { f32x4 zz = {0.f,0.f,0.f,0.f}; acc[pe][q] = zz; }
#pragma unroll
  for (int nt = 0; nt < 12; nt++) {
    bf16x8 w0 = *(const bf16x8*)&B1[(nt * 2 + 0) * 512 + ln * 8];
    bf16x8 w1 = *(const bf16x8*)&B1[(nt * 2 + 1) * 512 + ln * 8];
#pragma unroll
    for (int pe = 0; pe < 2; pe++) {
      acc[pe][nt] = mfma_bf16(af[pe][0], w0, acc[pe][nt]);
      acc[pe][nt] = mfma_bf16(af[pe][1], w1, acc[pe][nt]);
    }
  }
#pragma unroll
  for (int nt = 0; nt < 12; nt++) {
    int n = nt * 16 + l16;
    float bias = biasL[n];
#pragma unroll
    for (int pe = 0; pe < 2; pe++)
#pragma unroll
      for (int r = 0; r < 4; r++) {
        float v = acc[pe][nt][r] + bias;
        A2[pe][wv * 16 + quad * 4 + r][n] = (bf16)(v > 0.f ? v : 0.f);
      }
  }
  __syncthreads();
  bf16x8 a2[2][3][2];
#pragma unroll
  for (int pe = 0; pe < 2; pe++)
#pragma unroll
    for (int kt = 0; kt < 3; kt++)
#pragma unroll
      for (int kf = 0; kf < 2; kf++)
        a2[pe][kt][kf] = *(const bf16x8*)&A2[pe][m][kt * 64 + kf * 32 + quad * 8];
  __syncthreads();  // A2 dead -> S may overwrite
  f32x4 acc2[2][12];
#pragma unroll
  for (int pe = 0; pe < 2; pe++)
#pragma unroll
    for (int q = 0; q < 12; q++) { f32x4 zz = {0.f,0.f,0.f,0.f}; acc2[pe][q] = zz; }
#pragma unroll
  for (int kt = 0; kt < 3; kt++)
#pragma unroll
    for (int nt = 0; nt < 4; nt++) {
      bf16x8 w0 = *(const bf16x8*)&B2[kt * 4096 + (nt * 2 + 0) * 512 + ln * 8];
      bf16x8 w1 = *(const bf16x8*)&B2[kt * 4096 + (nt * 2 + 1) * 512 + ln * 8];
#pragma unroll
      for (int pe = 0; pe < 2; pe++) {
        acc2[pe][kt * 4 + nt] = mfma_bf16(a2[pe][kt][0], w0, acc2[pe][kt * 4 + nt]);
        acc2[pe][kt * 4 + nt] = mfma_bf16(a2[pe][kt][1], w1, acc2[pe][kt * 4 + nt]);
      }
    }
#pragma unroll
  for (int pe = 0; pe < 2; pe++)
#pragma unroll
    for (int r = 0; r < 4; r++) {
      int b = wv * 16 + quad * 4 + r;
      float z0 = zL[pe][b][0], z1 = zL[pe][b][1], z2 = zL[pe][b][2];
#pragma unroll
      for (int nt = 0; nt < 4; nt++) {
        int o = nt * 16 + l16;
        float h0 = acc2[pe][nt][r]     + biasL[192 + o];       h0 = h0 > 0.f ? h0 : 0.f;
        float h1 = acc2[pe][4 + nt][r] + biasL[192 + 64 + o];  h1 = h1 > 0.f ? h1 : 0.f;
        float h2 = acc2[pe][8 + nt][r] + biasL[192 + 128 + o]; h2 = h2 > 0.f ? h2 : 0.f;
        S[pe][b][o] = (bf16)((h0 * z0 + h1 * z1 + h2 * z2) * (1.0f / 3.0f));
      }
    }
  __syncthreads();
  bf16* dst = mixall + (size_t)t * NE * 4096;
  for (int u = tid; u < 1024; u += 256) {
    int pe = u >> 9, c = u & 511, b = c >> 3, j = c & 7;
    *(bf16x8*)(dst + (size_t)(e0 + pe) * 4096 + b * 64 + j * 8) = *(const bf16x8*)&S[pe][b][j * 8];
  }
}

// ---------------------------------------------------------------------------
// gru7: runs the 7 conditioning GRU updates for 2 edges entirely in one
// kernel; h lives in LDS. Writes h(t) snapshots in place over mixall[t].
// ---------------------------------------------------------------------------
__global__ __launch_bounds__(256, 2) void gru7(
    bf16* __restrict__ mixall,
    const bf16* __restrict__ GI, const bf16* __restrict__ GH,
    const float* __restrict__ gbi, const float* __restrict__ gbh) {
  __shared__ __align__(16) bf16 S[2][64][72];
  __shared__ float gb[384];  // gbi | gbh
  int e0 = blockIdx.x * 2, tid = threadIdx.x;
  for (int u = tid; u < 384; u += 256)
    gb[u] = (u < 192) ? gbi[u] : gbh[u - 192];
  for (int u = tid; u < 1024; u += 256) {
    int pe = u >> 9, c = u & 511, b = c >> 3, j = c & 7;
    *(bf16x8*)&S[pe][b][j * 8] =
        *(const bf16x8*)(mixall + (size_t)(e0 + pe) * 4096 + b * 64 + j * 8);
  }
  __syncthreads();
  int wv = tid >> 6, ln = tid & 63, quad = ln >> 4, l16 = ln & 15;
  int m = wv * 16 + l16;
  for (int t = 1; t < NSTEP; t++) {
    bf16* mt = mixall + (size_t)t * NE * 4096;
    bf16x8 ai[2][2], ah[2][2];
#pragma unroll
    for (int pe = 0; pe < 2; pe++) {
      const bf16* mrow = mt + (size_t)(e0 + pe) * 4096 + m * 64;
#pragma unroll
      for (int kf = 0; kf < 2; kf++) {
        ai[pe][kf] = *(const bf16x8*)(mrow + kf * 32 + quad * 8);
        ah[pe][kf] = *(const bf16x8*)&S[pe][m][kf * 32 + quad * 8];
      }
    }
    f32x4 gri[2][8], gni[2][4], gnh[2][4];
#pragma unroll
    for (int pe = 0; pe < 2; pe++) {
#pragma unroll
      for (int q = 0; q < 8; q++) { f32x4 zz = {0.f,0.f,0.f,0.f}; gri[pe][q] = zz; }
#pragma unroll
      for (int q = 0; q < 4; q++) { f32x4 zz = {0.f,0.f,0.f,0.f}; gni[pe][q] = zz; gnh[pe][q] = zz; }
    }
#pragma unroll
    for (int nt = 0; nt < 8; nt++) {
      bf16x8 wi0 = *(const bf16x8*)&GI[(nt * 2 + 0) * 512 + ln * 8];
      bf16x8 wi1 = *(const bf16x8*)&GI[(nt * 2 + 1) * 512 + ln * 8];
      bf16x8 wh0 = *(const bf16x8*)&GH[(nt * 2 + 0) * 512 + ln * 8];
      bf16x8 wh1 = *(const bf16x8*)&GH[(nt * 2 + 1) * 512 + ln * 8];
#pragma unroll
      for (int pe = 0; pe < 2; pe++) {
        gri[pe][nt] = mfma_bf16(ai[pe][0], wi0, gri[pe][nt]);
        gri[pe][nt] = mfma_bf16(ai[pe][1], wi1, gri[pe][nt]);
        gri[pe][nt] = mfma_bf16(ah[pe][0], wh0, gri[pe][nt]);
        gri[pe][nt] = mfma_bf16(ah[pe][1], wh1, gri[pe][nt]);
      }
    }
#pragma unroll
    for (int nt = 8; nt < 12; nt++) {
      bf16x8 wi0 = *(const bf16x8*)&GI[(nt * 2 + 0) * 512 + ln * 8];
      bf16x8 wi1 = *(const bf16x8*)&GI[(nt * 2 + 1) * 512 + ln * 8];
      bf16x8 wh0 = *(const bf16x8*)&GH[(nt * 2 + 0) * 512 + ln * 8];
      bf16x8 wh1 = *(const bf16x8*)&GH[(nt * 2 + 1) * 512 + ln * 8];
#pragma unroll
      for (int pe = 0; pe < 2; pe++) {
        gni[pe][nt - 8] = mfma_bf16(ai[pe][0], wi0, gni[pe][nt - 8]);
        gni[pe][nt - 8] = mfma_bf16(ai[pe][1], wi1, gni[pe][nt - 8]);
        gnh[pe][nt - 8] = mfma_bf16(ah[pe][0], wh0, gnh[pe][nt - 8]);
        gnh[pe][nt - 8] = mfma_bf16(ah[pe][1], wh1, gnh[pe][nt - 8]);
      }
    }
#pragma unroll
    for (int pe = 0; pe < 2; pe++)
#pragma unroll
      for (int r = 0; r < 4; r++) {
        int b = wv * 16 + quad * 4 + r;
#pragma unroll
        for (int nt = 0; nt < 4; nt++) {
          int o = nt * 16 + l16;
          float xr = gri[pe][nt][r]     + gb[o]      + gb[192 + o];
          float xi = gri[pe][4 + nt][r] + gb[64 + o] + gb[192 + 64 + o];
          float xn = gni[pe][nt][r] + gb[128 + o];
          float hn = gnh[pe][nt][r] + gb[192 + 128 + o];
          float rg = sigm(xr);
          float ig = sigm(xi);
          float ng = tanh_f(xn + rg * hn);
          float hv = (float)S[pe][b][o];
          S[pe][b][o] = (bf16)((1.0f - ig) * ng + ig * hv);
        }
      }
    __syncthreads();
    for (int u = tid; u < 1024; u += 256) {
      int pe = u >> 9, c = u & 511, b = c >> 3, j = c & 7;
      *(bf16x8*)(mt + (size_t)(e0 + pe) * 4096 + b * 64 + j * 8) = *(const bf16x8*)&S[pe][b][j * 8];
    }
    __syncthreads();
  }
}

// ---------------------------------------------------------------------------
// node8: all 8 conditioning node steps in one kernel; h_node in LDS.
// Writes outputs for t=0..7; at t=7 emits xf/xb (= x_m(7)) and hnode.
// ---------------------------------------------------------------------------
__global__ __launch_bounds__(256) void node8(
    const float* __restrict__ x, const bf16* __restrict__ mixall,
    float* __restrict__ xf, bf16* __restrict__ xb, float* __restrict__ hnode,
    const bf16* __restrict__ GN,
    const float* __restrict__ gnbi, const float* __restrict__ gnbh,
    const bf16* __restrict__ OW1, const float* __restrict__ ob1,
    const bf16* __restrict__ OW2, const float* __restrict__ ob2,
    const bf16* __restrict__ OW3, const float* __restrict__ ob3,
    float* __restrict__ out) {
  __shared__ float aggf[16][64];
  __shared__ float xinf[16][32];
  __shared__ float hnf[16][96];   // persistent h_node (fp32)
  __shared__ __align__(16) bf16 c0b[16][112];
  __shared__ __align__(16) bf16 hvb[16][112];
  __shared__ float gsum[2][16][290];
  __shared__ __align__(16) bf16 cnb[16][112];
  __shared__ __align__(16) bf16 s1b[16][112];
  __shared__ __align__(16) bf16 s2b[16][112];
  int nq = blockIdx.x, n = nq >> 2, q = nq & 3;
  int tid = threadIdx.x;
  int wv = tid >> 6, ln = tid & 63, quad = ln >> 4, l16 = ln & 15;
  for (int t = 0; t < NSTEP; t++) {
    __syncthreads();
    const bf16* hed = mixall + (size_t)t * NE * 4096;
    {
      int r = tid >> 4, o4 = tid & 15;
      const bf16x4* bp = (const bf16x4*)hed + (size_t)n * 31 * 1024 + (q * 16 + r) * 16 + o4;
      float sx = 0.f, sy = 0.f, sz = 0.f, sw = 0.f;
#pragma unroll
      for (int e2 = 0; e2 < 31; e2++) {
        bf16x4 v = bp[e2 * 1024];
        sx += (float)v[0]; sy += (float)v[1]; sz += (float)v[2]; sw += (float)v[3];
      }
      const float inv = 1.0f / 31.0f;
      sx *= inv; sy *= inv; sz *= inv; sw *= inv;
      int o = o4 * 4;
      aggf[r][o] = sx; aggf[r][o + 1] = sy; aggf[r][o + 2] = sz; aggf[r][o + 3] = sw;
      c0b[r][32 + o] = (bf16)sx; c0b[r][33 + o] = (bf16)sy;
      c0b[r][34 + o] = (bf16)sz; c0b[r][35 + o] = (bf16)sw;
    }
    if (tid < 128) {
      int r = tid >> 3, d0 = (tid & 7) * 4;
      int b = q * 16 + r;
#pragma unroll
      for (int k = 0; k < 4; k++) {
        float v = x[((b * 32 + n) * 32 + d0 + k) * 8 + t];
        xinf[r][d0 + k] = v;
        c0b[r][d0 + k] = (bf16)v;
      }
    }
    if (t > 0) {
      int r = tid >> 4, cb = (tid & 15) * 6;
#pragma unroll
      for (int k = 0; k < 6; k++) hvb[r][cb + k] = (bf16)hnf[r][cb + k];
    }
    __syncthreads();
    if (t > 0) {
      int mat = wv >> 1, sel = wv & 1;
      const bf16(*Ab)[112] = mat ? hvb : c0b;
      bf16x8 af[3];
#pragma unroll
      for (int kf = 0; kf < 3; kf++)
        af[kf] = *(const bf16x8*)&Ab[l16][kf * 32 + quad * 8];
      const bf16* W = GN + mat * 27648;
      f32x4 accn[9];
#pragma unroll
      for (int q2 = 0; q2 < 9; q2++) { f32x4 zz = {0.f,0.f,0.f,0.f}; accn[q2] = zz; }
#pragma unroll
      for (int nt2 = 0; nt2 < 9; nt2++) {
        int nt = sel * 9 + nt2;
#pragma unroll
        for (int kf = 0; kf < 3; kf++) {
          bf16x8 bfrag = *(const bf16x8*)&W[((nt * 3 + kf) * 64 + ln) * 8];
          accn[nt2] = mfma_bf16(af[kf], bfrag, accn[nt2]);
        }
      }
#pragma unroll
      for (int nt2 = 0; nt2 < 9; nt2++) {
        int col = (sel * 9 + nt2) * 16 + l16;
#pragma unroll
        for (int rr = 0; rr < 4; rr++)
          gsum[mat][quad * 4 + rr][col] = accn[nt2][rr];
      }
    }
    __syncthreads();
    {
      int r = tid >> 4, cb = (tid & 15) * 6;
      int row = n * 64 + q * 16 + r;
#pragma unroll
      for (int k = 0; k < 6; k++) {
        int c = cb + k;
        float v;
        if (t > 0) {
          float xr = gsum[0][r][c] + gnbi[c] + gsum[1][r][c] + gnbh[c];
          float xi = gsum[0][r][96 + c] + gnbi[96 + c] + gsum[1][r][96 + c] + gnbh[96 + c];
          float xn = gsum[0][r][192 + c] + gnbi[192 + c];
          float hn = gsum[1][r][192 + c] + gnbh[192 + c];
          float rg = sigm(xr);
          float ig = sigm(xi);
          float ng = tanh_f(xn + rg * hn);
          v = (1.0f - ig) * ng + ig * hnf[r][c];
        } else {
          v = (c < 32) ? xinf[r][c] : aggf[r][c - 32];
        }
        cnb[r][c] = (bf16)v;
        hnf[r][c] = v;
        if (t == NSTEP - 1) hnode[row * 96 + c] = v;
      }
    }
    __syncthreads();
    {
      bf16x8 af[3];
#pragma unroll
      for (int kf = 0; kf < 3; kf++)
        af[kf] = *(const bf16x8*)&cnb[l16][kf * 32 + quad * 8];
      f32x4 accn = {0.f, 0.f, 0.f, 0.f};
#pragma unroll
      for (int kf = 0; kf < 3; kf++) {
        bf16x8 bfrag = *(const bf16x8*)&OW1[((wv * 3 + kf) * 64 + ln) * 8];
        accn = mfma_bf16(af[kf], bfrag, accn);
      }
      int col = wv * 16 + l16;
      float bias = ob1[col];
#pragma unroll
      for (int rr = 0; rr < 4; rr++) {
        float vv = accn[rr] + bias;
        s1b[quad * 4 + rr][col] = (bf16)(vv > 0.f ? vv : 0.f);
      }
    }
    __syncthreads();
    {
      bf16x8 af[2];
#pragma unroll
      for (int kf = 0; kf < 2; kf++)
        af[kf] = *(const bf16x8*)&s1b[l16][kf * 32 + quad * 8];
      f32x4 accn = {0.f, 0.f, 0.f, 0.f};
#pragma unroll
      for (int kf = 0; kf < 2; kf++) {
        bf16x8 bfrag = *(const bf16x8*)&OW2[((wv * 2 + kf) * 64 + ln) * 8];
        accn = mfma_bf16(af[kf], bfrag, accn);
      }
      int col = wv * 16 + l16;
      float bias = ob2[col];
#pragma unroll
      for (int rr = 0; rr < 4; rr++) {
        float vv = accn[rr] + bias;
        s2b[quad * 4 + rr][col] = (bf16)(vv > 0.f ? vv : 0.f);
      }
    }
    __syncthreads();
    if (wv < 2) {
      bf16x8 af[2];
#pragma unroll
      for (int kf = 0; kf < 2; kf++)
        af[kf] = *(const bf16x8*)&s2b[l16][kf * 32 + quad * 8];
      f32x4 accn = {0.f, 0.f, 0.f, 0.f};
#pragma unroll
      for (int kf = 0; kf < 2; kf++) {
        bf16x8 bfrag = *(const bf16x8*)&OW3[((wv * 2 + kf) * 64 + ln) * 8];
        accn = mfma_bf16(af[kf], bfrag, accn);
      }
      int d = wv * 16 + l16;
      float bias = ob3[d];
#pragma unroll
      for (int rr = 0; rr < 4; rr++) {
        int r = quad * 4 + rr;
        int b = q * 16 + r;
        float xm = xinf[r][d] + accn[rr] + bias;
        int base = (b * 32 + n) * 32 + d;
        out[524288 + base * 16 + t] = xm;
        out[1572864 + base * 16 + t] = xm;
        if (t == NSTEP - 1) {
          xf[n * 2048 + b * 32 + d] = xm;
          xb[n * 2048 + b * 32 + d] = (bf16)xm;
        }
      }
    }
  }
}

// ---------------------------------------------------------------------------
// edge_step (prediction, t>=8): round-7 validated. Stage xb, layer1, layer2,
// z-mix, GRU vs hed (in place). 496 blocks.
// ---------------------------------------------------------------------------
__global__ __launch_bounds__(256, 2) void edge_step(
    const bf16* __restrict__ xb, const int* __restrict__ es,
    const float* __restrict__ z,
    const bf16* __restrict__ B1, const bf16* __restrict__ B2,
    const float* __restrict__ mb1, const float* __restrict__ mb2,
    const bf16* __restrict__ GI, const bf16* __restrict__ GH,
    const float* __restrict__ gbi, const float* __restrict__ gbh,
    bf16* __restrict__ hed) {
  __shared__ __align__(16) char scrbuf[51200];
  __shared__ float zL[2][64][3];
  __shared__ float biasL[768];  // mb1 | mb2 | gbi | gbh
  bf16 (*A)[64][72]   = (bf16(*)[64][72])scrbuf;
  bf16 (*A2)[64][200] = (bf16(*)[64][200])scrbuf;

  int e0 = blockIdx.x * 2, tid = threadIdx.x;
  int c0_ = es[e0],     r0 = es[NE + e0];
  int c1_ = es[e0 + 1], r1 = es[NE + e0 + 1];
  for (int u = tid; u < 768; u += 256)
    biasL[u] = (u < 192) ? mb1[u] : (u < 384) ? mb2[u - 192]
             : (u < 576) ? gbi[u - 384] : gbh[u - 576];
  for (int u = tid; u < 384; u += 256) {
    int pe = u / 192, rem = u % 192, b = rem / 3, k = rem % 3;
    zL[pe][b][k] = z[(b * NE + e0 + pe) * 3 + k];
  }
  for (int u = tid; u < 1024; u += 256) {
    int pe = u >> 9, c = u & 511, b = c >> 3, i8 = c & 7;
    int nrow = pe ? r1 : r0, ncol = pe ? c1_ : c0_;
    const bf16* src = (i8 < 4) ? (xb + nrow * 2048 + b * 32 + i8 * 8)
                               : (xb + ncol * 2048 + b * 32 + (i8 - 4) * 8);
    *(bf16x8*)&A[pe][b][i8 * 8] = *(const bf16x8*)src;
  }
  __syncthreads();
  int wv = tid >> 6, ln = tid & 63, quad = ln >> 4, l16 = ln & 15;
  int m = wv * 16 + l16;
  bf16x8 af[2][2];
#pragma unroll
  for (int pe = 0; pe < 2; pe++)
#pragma unroll
    for (int kf = 0; kf < 2; kf++)
      af[pe][kf] = *(const bf16x8*)&A[pe][m][kf * 32 + quad * 8];
  __syncthreads();
  f32x4 acc[2][12];
#pragma unroll
  for (int pe = 0; pe < 2; pe++)
#pragma unroll
    for (int q = 0; q < 12; q++) { f32x4 zz = {0.f,0.f,0.f,0.f}; acc[pe][q] = zz; }
#pragma unroll
  for (int nt = 0; nt < 12; nt++) {
    bf16x8 w0 = *(const bf16x8*)&B1[(nt * 2 + 0) * 512 + ln * 8];
    bf16x8 w1 = *(const bf16x8*)&B1[(nt * 2 + 1) * 512 + ln * 8];
#pragma unroll
    for (int pe = 0; pe < 2; pe++) {
      acc[pe][nt] = mfma_bf16(af[pe][0], w0, acc[pe][nt]);
      acc[pe][nt] = mfma_bf16(af[pe][1], w1, acc[pe][nt]);
    }
  }
#pragma unroll
  for (int nt = 0; nt < 12; nt++) {
    int n = nt * 16 + l16;
    float bias = biasL[n];
#pragma unroll
    for (int pe = 0; pe < 2; pe++)
#pragma unroll
      for (int r = 0; r < 4; r++) {
        float v = acc[pe][nt][r] + bias;
        A2[pe][wv * 16 + quad * 4 + r][n] = (bf16)(v > 0.f ? v : 0.f);
      }
  }
  __syncthreads();
  bf16x8 a2[2][3][2];
#pragma unroll
  for (int pe = 0; pe < 2; pe++)
#pragma unroll
    for (int kt = 0; kt < 3; kt++)
#pragma unroll
      for (int kf = 0; kf < 2; kf++)
        a2[pe][kt][kf] = *(const bf16x8*)&A2[pe][m][kt * 64 + kf * 32 + quad * 8];
  __syncthreads();
  f32x4 acc2[2][12];
#pragma unroll
  for (int pe = 0; pe < 2; pe++)
#pragma unroll
    for (int q = 0; q < 12; q++) { f32x4 zz = {0.f,0.f,0.f,0.f}; acc2[pe][q] = zz; }
#pragma unroll
  for (int kt = 0; kt < 3; kt++)
#pragma unroll
    for (int nt = 0; nt < 4; nt++) {
      bf16x8 w0 = *(const bf16x8*)&B2[kt * 4096 + (nt * 2 + 0) * 512 + ln * 8];
      bf16x8 w1 = *(const bf16x8*)&B2[kt * 4096 + (nt * 2 + 1) * 512 + ln * 8];
#pragma unroll
      for (int pe = 0; pe < 2; pe++) {
        acc2[pe][kt * 4 + nt] = mfma_bf16(a2[pe][kt][0], w0, acc2[pe][kt * 4 + nt]);
        acc2[pe][kt * 4 + nt] = mfma_bf16(a2[pe][kt][1], w1, acc2[pe][kt * 4 + nt]);
      }
    }
#pragma unroll
  for (int pe = 0; pe < 2; pe++)
#pragma unroll
    for (int r = 0; r < 4; r++) {
      int b = wv * 16 + quad * 4 + r;
      float z0 = zL[pe][b][0], z1 = zL[pe][b][1], z2 = zL[pe][b][2];
#pragma unroll
      for (int nt = 0; nt < 4; nt++) {
        int o = nt * 16 + l16;
        float h0 = acc2[pe][nt][r]     + biasL[192 + o];       h0 = h0 > 0.f ? h0 : 0.f;
        float h1 = acc2[pe][4 + nt][r] + biasL[192 + 64 + o];  h1 = h1 > 0.f ? h1 : 0.f;
        float h2 = acc2[pe][8 + nt][r] + biasL[192 + 128 + o]; h2 = h2 > 0.f ? h2 : 0.f;
        A[pe][b][o] = (bf16)((h0 * z0 + h1 * z1 + h2 * z2) * (1.0f / 3.0f));
      }
    }
  __syncthreads();
  bf16x8 ai[2][2], ah[2][2];
#pragma unroll
  for (int pe = 0; pe < 2; pe++) {
    const bf16* hrow = hed + (size_t)(e0 + pe) * 4096 + m * 64;
#pragma unroll
    for (int kf = 0; kf < 2; kf++) {
      ai[pe][kf] = *(const bf16x8*)&A[pe][m][kf * 32 + quad * 8];
      ah[pe][kf] = *(const bf16x8*)(hrow + kf * 32 + quad * 8);
    }
  }
  f32x4 gri[2][8], gni[2][4], gnh[2][4];
#pragma unroll
  for (int pe = 0; pe < 2; pe++) {
#pragma unroll
    for (int q = 0; q < 8; q++) { f32x4 zz = {0.f,0.f,0.f,0.f}; gri[pe][q] = zz; }
#pragma unroll
    for (int q = 0; q < 4; q++) { f32x4 zz = {0.f,0.f,0.f,0.f}; gni[pe][q] = zz; gnh[pe][q] = zz; }
  }
#pragma unroll
  for (int nt = 0; nt < 8; nt++) {
    bf16x8 wi0 = *(const bf16x8*)&GI[(nt * 2 + 0) * 512 + ln * 8];
    bf16x8 wi1 = *(const bf16x8*)&GI[(nt * 2 + 1) * 512 + ln * 8];
    bf16x8 wh0 = *(const bf16x8*)&GH[(nt * 2 + 0) * 512 + ln * 8];
    bf16x8 wh1 = *(const bf16x8*)&GH[(nt * 2 + 1) * 512 + ln * 8];
#pragma unroll
    for (int pe = 0; pe < 2; pe++) {
      gri[pe][nt] = mfma_bf16(ai[pe][0], wi0, gri[pe][nt]);
      gri[pe][nt] = mfma_bf16(ai[pe][1], wi1, gri[pe][nt]);
      gri[pe][nt] = mfma_bf16(ah[pe][0], wh0, gri[pe][nt]);
      gri[pe][nt] = mfma_bf16(ah[pe][1], wh1, gri[pe][nt]);
    }
  }
#pragma unroll
  for (int nt = 8; nt < 12; nt++) {
    bf16x8 wi0 = *(const bf16x8*)&GI[(nt * 2 + 0) * 512 + ln * 8];
    bf16x8 wi1 = *(const bf16x8*)&GI[(nt * 2 + 1) * 512 + ln * 8];
    bf16x8 wh0 = *(const bf16x8*)&GH[(nt * 2 + 0) * 512 + ln * 8];
    bf16x8 wh1 = *(const bf16x8*)&GH[(nt * 2 + 1) * 512 + ln * 8];
#pragma unroll
    for (int pe = 0; pe < 2; pe++) {
      gni[pe][nt - 8] = mfma_bf16(ai[pe][0], wi0, gni[pe][nt - 8]);
      gni[pe][nt - 8] = mfma_bf16(ai[pe][1], wi1, gni[pe][nt - 8]);
      gnh[pe][nt - 8] = mfma_bf16(ah[pe][0], wh0, gnh[pe][nt - 8]);
      gnh[pe][nt - 8] = mfma_bf16(ah[pe][1], wh1, gnh[pe][nt - 8]);
    }
  }
#pragma unroll
  for (int pe = 0; pe < 2; pe++)
#pragma unroll
    for (int r = 0; r < 4; r++) {
      int b = wv * 16 + quad * 4 + r;
#pragma unroll
      for (int nt = 0; nt < 4; nt++) {
        int o = nt * 16 + l16;
        float xr = gri[pe][nt][r]     + biasL[384 + o]      + biasL[576 + o];
        float xi = gri[pe][4 + nt][r] + biasL[384 + 64 + o] + biasL[576 + 64 + o];
        float xn = gni[pe][nt][r] + biasL[384 + 128 + o];
        float hn = gnh[pe][nt][r] + biasL[576 + 128 + o];
        float rg = sigm(xr);
        float ig = sigm(xi);
        float ng = tanh_f(xn + rg * hn);
        float hv = (float)hed[(size_t)(e0 + pe) * 4096 + b * 64 + o];
        A[pe][b][o] = (bf16)((1.0f - ig) * ng + ig * hv);
      }
    }
  __syncthreads();
  for (int u = tid; u < 1024; u += 256) {
    int pe = u >> 9, c = u & 511, b = c >> 3, j = c & 7;
    *(bf16x8*)(hed + (size_t)(e0 + pe) * 4096 + b * 64 + j * 8) = *(const bf16x8*)&A[pe][b][j * 8];
  }
}

// ---------------------------------------------------------------------------
// node_pred (t>=8): agg + node GRU (MFMA) + out-MLP; writes out, xf, xb, hnode.
// ---------------------------------------------------------------------------
__global__ __launch_bounds__(256) void node_pred(
    const bf16* __restrict__ hed,
    float* __restrict__ xf, bf16* __restrict__ xb, float* __restrict__ hnode,
    const bf16* __restrict__ GN,
    const float* __restrict__ gnbi, const float* __restrict__ gnbh,
    const bf16* __restrict__ OW1, const float* __restrict__ ob1,
    const bf16* __restrict__ OW2, const float* __restrict__ ob2,
    const bf16* __restrict__ OW3, const float* __restrict__ ob3,
    float* __restrict__ out, int t) {
  __shared__ float aggf[16][64];
  __shared__ float xinf[16][32];
  __shared__ float hvf[16][96];
  __shared__ __align__(16) bf16 c0b[16][112];
  __shared__ __align__(16) bf16 hvb[16][112];
  __shared__ float gsum[2][16][290];
  __shared__ __align__(16) bf16 cnb[16][112];
  __shared__ __align__(16) bf16 s1b[16][112];
  __shared__ __align__(16) bf16 s2b[16][112];
  int nq = blockIdx.x, n = nq >> 2, q = nq & 3;
  int tid = threadIdx.x;
  {
    int r = tid >> 4, o4 = tid & 15;
    const bf16x4* bp = (const bf16x4*)hed + (size_t)n * 31 * 1024 + (q * 16 + r) * 16 + o4;
    float sx = 0.f, sy = 0.f, sz = 0.f, sw = 0.f;
#pragma unroll
    for (int e2 = 0; e2 < 31; e2++) {
      bf16x4 v = bp[e2 * 1024];
      sx += (float)v[0]; sy += (float)v[1]; sz += (float)v[2]; sw += (float)v[3];
    }
    const float inv = 1.0f / 31.0f;
    sx *= inv; sy *= inv; sz *= inv; sw *= inv;
    int o = o4 * 4;
    aggf[r][o] = sx; aggf[r][o + 1] = sy; aggf[r][o + 2] = sz; aggf[r][o + 3] = sw;
    c0b[r][32 + o] = (bf16)sx; c0b[r][33 + o] = (bf16)sy;
    c0b[r][34 + o] = (bf16)sz; c0b[r][35 + o] = (bf16)sw;
  }
  if (tid < 128) {
    int r = tid >> 3, d0 = (tid & 7) * 4;
    int b = q * 16 + r;
#pragma unroll
    for (int k = 0; k < 4; k++) {
      float v = xf[n * 2048 + b * 32 + d0 + k];
      xinf[r][d0 + k] = v;
      c0b[r][d0 + k] = (bf16)v;
    }
  }
  {
    int r = tid >> 4, cb = (tid & 15) * 6;
    int row = n * 64 + q * 16 + r;
#pragma unroll
    for (int k = 0; k < 6; k++) {
      float v = hnode[row * 96 + cb + k];
      hvf[r][cb + k] = v;
      hvb[r][cb + k] = (bf16)v;
    }
  }
  __syncthreads();
  int wv = tid >> 6, ln = tid & 63, quad = ln >> 4, l16 = ln & 15;
  {
    int mat = wv >> 1, sel = wv & 1;
    const bf16(*Ab)[112] = mat ? hvb : c0b;
    bf16x8 af[3];
#pragma unroll
    for (int kf = 0; kf < 3; kf++)
      af[kf] = *(const bf16x8*)&Ab[l16][kf * 32 + quad * 8];
    const bf16* W = GN + mat * 27648;
    f32x4 accn[9];
#pragma unroll
    for (int q2 = 0; q2 < 9; q2++) { f32x4 zz = {0.f,0.f,0.f,0.f}; accn[q2] = zz; }
#pragma unroll
    for (int nt2 = 0; nt2 < 9; nt2++) {
      int nt = sel * 9 + nt2;
#pragma unroll
      for (int kf = 0; kf < 3; kf++) {
        bf16x8 bfrag = *(const bf16x8*)&W[((nt * 3 + kf) * 64 + ln) * 8];
        accn[nt2] = mfma_bf16(af[kf], bfrag, accn[nt2]);
      }
    }
#pragma unroll
    for (int nt2 = 0; nt2 < 9; nt2++) {
      int col = (sel * 9 + nt2) * 16 + l16;
#pragma unroll
      for (int rr = 0; rr < 4; rr++)
        gsum[mat][quad * 4 + rr][col] = accn[nt2][rr];
    }
  }
  __syncthreads();
  {
    int r = tid >> 4, cb = (tid & 15) * 6;
    int row = n * 64 + q * 16 + r;
#pragma unroll
    for (int k = 0; k < 6; k++) {
      int c = cb + k;
      float xr = gsum[0][r][c] + gnbi[c] + gsum[1][r][c] + gnbh[c];
      float xi = gsum[0][r][96 + c] + gnbi[96 + c] + gsum[1][r][96 + c] + gnbh[96 + c];
      float xn = gsum[0][r][192 + c] + gnbi[192 + c];
      float hn = gsum[1][r][192 + c] + gnbh[192 + c];
      float rg = sigm(xr);
      float ig = sigm(xi);
      float ng = tanh_f(xn + rg * hn);
      float v = (1.0f - ig) * ng + ig * hvf[r][c];
      cnb[r][c] = (bf16)v;
      hnode[row * 96 + c] = v;
    }
  }
  __syncthreads();
  {
    bf16x8 af[3];
#pragma unroll
    for (int kf = 0; kf < 3; kf++)
      af[kf] = *(const bf16x8*)&cnb[l16][kf * 32 + quad * 8];
    f32x4 accn = {0.f, 0.f, 0.f, 0.f};
#pragma unroll
    for (int kf = 0; kf < 3; kf++) {
      bf16x8 bfrag = *(const bf16x8*)&OW1[((wv * 3 + kf) * 64 + ln) * 8];
      accn = mfma_bf16(af[kf], bfrag, accn);
    }
    int col = wv * 16 + l16;
    float bias = ob1[col];
#pragma unroll
    for (int rr = 0; rr < 4; rr++) {
      float vv = accn[rr] + bias;
      s1b[quad * 4 + rr][col] = (bf16)(vv > 0.f ? vv : 0.f);
    }
  }
  __syncthreads();
  {
    bf16x8 af[2];
#pragma unroll
    for (int kf = 0; kf < 2; kf++)
      af[kf] = *(const bf16x8*)&s1b[l16][kf * 32 + quad * 8];
    f32x4 accn = {0.f, 0.f, 0.f, 0.f};
#pragma unroll
    for (int kf = 0; kf < 2; kf++) {
      bf16x8 bfrag = *(const bf16x8*)&OW2[((wv * 2 + kf) * 64 + ln) * 8];
      accn = mfma_bf16(af[kf], bfrag, accn);
    }
    int col = wv * 16 + l16;
    float bias = ob2[col];
#pragma unroll
    for (int rr = 0; rr < 4; rr++) {
      float vv = accn[rr] + bias;
      s2b[quad * 4 + rr][col] = (bf16)(vv > 0.f ? vv : 0.f);
    }
  }
  __syncthreads();
  if (wv < 2) {
    bf16x8 af[2];
#pragma unroll
    for (int kf = 0; kf < 2; kf++)
      af[kf] = *(const bf16x8*)&s2b[l16][kf * 32 + quad * 8];
    f32x4 accn = {0.f, 0.f, 0.f, 0.f};
#pragma unroll
    for (int kf = 0; kf < 2; kf++) {
      bf16x8 bfrag = *(const bf16x8*)&OW3[((wv * 2 + kf) * 64 + ln) * 8];
      accn = mfma_bf16(af[kf], bfrag, accn);
    }
    int d = wv * 16 + l16;
    float bias = ob3[d];
#pragma unroll
    for (int rr = 0; rr < 4; rr++) {
      int r = quad * 4 + rr;
      int b = q * 16 + r;
      float xm = xinf[r][d] + accn[rr] + bias;
      int base = (b * 32 + n) * 32 + d;
      out[524288 + base * 16 + t] = xm;
      out[1572864 + base * 16 + t] = xm;
      out[base * 8 + (t - NSTEP)] = xm;
      xf[n * 2048 + b * 32 + d] = xm;
      xb[n * 2048 + b * 32 + d] = (bf16)xm;
    }
  }
}

extern "C" void kernel_launch(void* const* d_in, const int* in_sizes, int n_in,
                              void* d_out, int out_size, void* d_ws, size_t ws_size,
                              hipStream_t stream) {
  const float* x     = (const float*)d_in[0];
  const float* z     = (const float*)d_in[1];
  const int*   es    = (const int*)d_in[2];
  const float* msgW1 = (const float*)d_in[6];
  const float* msgb1 = (const float*)d_in[7];
  const float* msgW2 = (const float*)d_in[8];
  const float* msgb2 = (const float*)d_in[9];
  const float* oW1   = (const float*)d_in[10];
  const float* ob1   = (const float*)d_in[11];
  const float* oW2   = (const float*)d_in[12];
  const float* ob2   = (const float*)d_in[13];
  const float* oW3   = (const float*)d_in[14];
  const float* ob3   = (const float*)d_in[15];
  const float* geWi  = (const float*)d_in[16];
  const float* gebi  = (const float*)d_in[17];
  const float* geWh  = (const float*)d_in[18];
  const float* gebh  = (const float*)d_in[19];
  const float* gnWi  = (const float*)d_in[20];
  const float* gnbi  = (const float*)d_in[21];
  const float* gnWh  = (const float*)d_in[22];
  const float* gnbh  = (const float*)d_in[23];
  float* out = (float*)d_out;

  char* p = (char*)d_ws;
  bf16*  mixall = (bf16*)p;  p += (size_t)NSTEP * NE * 4096 * 2;  // 65 MB
  bf16*  xall   = (bf16*)p;  p += (size_t)NSTEP * 65536 * 2;      // 1 MB
  float* xf     = (float*)p; p += 65536 * 4;
  bf16*  xb     = (bf16*)p;  p += 65536 * 2;
  float* hnode  = (float*)p; p += 196608 * 4;
  bf16*  B1sw   = (bf16*)p;  p += 12288 * 2;
  bf16*  B2sw   = (bf16*)p;  p += 12288 * 2;
  bf16*  GIsw   = (bf16*)p;  p += 12288 * 2;
  bf16*  GHsw   = (bf16*)p;  p += 12288 * 2;
  bf16*  GNsw   = (bf16*)p;  p += 55296 * 2;
  bf16*  OW1s   = (bf16*)p;  p += 6144 * 2;
  bf16*  OW2s   = (bf16*)p;  p += 4096 * 2;
  bf16*  OW3s   = (bf16*)p;  p += 2048 * 2;

  bf16* hed = mixall + (size_t)(NSTEP - 1) * NE * 4096;  // h(7), updated in place

  prep_weights<<<204, 256, 0, stream>>>(msgW1, msgW2, geWi, geWh, gnWi, gnWh,
                                        oW1, oW2, oW3,
                                        B1sw, B2sw, GIsw, GHsw, GNsw,
                                        OW1s, OW2s, OW3s);
  copy_xall<<<2048, 256, 0, stream>>>(x, xall);
  mix8x<<<8 * 496, 256, 0, stream>>>(xall, es, z, B1sw, B2sw, msgb1, msgb2, mixall);
  gru7<<<496, 256, 0, stream>>>(mixall, GIsw, GHsw, gebi, gebh);
  node8<<<128, 256, 0, stream>>>(x, mixall, xf, xb, hnode, GNsw, gnbi, gnbh,
                                 OW1s, ob1, OW2s, ob2, OW3s, ob3, out);
  for (int t = NSTEP; t < NTT; t++) {
    edge_step<<<496, 256, 0, stream>>>(xb, es, z, B1sw, B2sw, msgb1, msgb2,
                                       GIsw, GHsw, gebi, gebh, hed);
    node_pred<<<128, 256, 0, stream>>>(hed, xf, xb, hnode, GNsw, gnbi, gnbh,
                                       OW1s, ob1, OW2s, ob2, OW3s, ob3, out, t);
  }
}